// Round 1
// baseline (584.417 us; speedup 1.0000x reference)
//
#include <hip/hip_runtime.h>
#include <hip/hip_bf16.h>

#define NBATCH 4
#define NSEQ   1024
#define BNN    4096
#define CIN    128
#define COUT   256
#define RDIM   32
#define NEDGE  65536

// t_s = x_s (copy), t_t = x_t (copy); scatter kernels then add neighbor sums.
__global__ void copy2_kernel(const float* __restrict__ a, float* __restrict__ ta,
                             const float* __restrict__ b, float* __restrict__ tb) {
    int i = blockIdx.x * blockDim.x + threadIdx.x;      // float4 index, 131072 total
    ((float4*)ta)[i] = ((const float4*)a)[i];
    ((float4*)tb)[i] = ((const float4*)b)[i];
}

// agg[dst] += x[src], 128-wide features. One (edge, 4-feature) per thread.
__global__ void scatter128(const float* __restrict__ x, const int* __restrict__ ei,
                           float* __restrict__ t) {
    int gid = blockIdx.x * blockDim.x + threadIdx.x;    // NEDGE*32 threads
    int e  = gid >> 5;
    int c4 = (gid & 31) << 2;
    int src = ei[e], dst = ei[NEDGE + e];
    const float4 v = *(const float4*)(x + (size_t)src * CIN + c4);
    float* p = t + (size_t)dst * CIN + c4;
    atomicAdd(p + 0, v.x); atomicAdd(p + 1, v.y);
    atomicAdd(p + 2, v.z); atomicAdd(p + 3, v.w);
}

// 32-wide variant.
__global__ void scatter32(const float* __restrict__ x, const int* __restrict__ ei,
                          float* __restrict__ t) {
    int gid = blockIdx.x * blockDim.x + threadIdx.x;    // NEDGE*8 threads
    int e  = gid >> 3;
    int c4 = (gid & 7) << 2;
    int src = ei[e], dst = ei[NEDGE + e];
    const float4 v = *(const float4*)(x + (size_t)src * RDIM + c4);
    float* p = t + (size_t)dst * RDIM + c4;
    atomicAdd(p + 0, v.x); atomicAdd(p + 1, v.y);
    atomicAdd(p + 2, v.z); atomicAdd(p + 3, v.w);
}

// h = relu(t @ W1 + b1) : [4096,128] @ [128,256]. 8 rows per block, thread = out col.
__global__ void psi1_gemm(const float* __restrict__ t, const float* __restrict__ W1,
                          const float* __restrict__ b1, float* __restrict__ h) {
    __shared__ float rows[8][CIN];
    int r0 = blockIdx.x * 8;
    int tid = threadIdx.x;
    {
        int rr = tid >> 5, c4 = (tid & 31) << 2;
        *(float4*)&rows[rr][c4] = *(const float4*)(t + (size_t)(r0 + rr) * CIN + c4);
    }
    __syncthreads();
    float acc[8];
    float bias = b1[tid];
#pragma unroll
    for (int r = 0; r < 8; r++) acc[r] = bias;
    for (int k = 0; k < CIN; k++) {
        float w = W1[k * COUT + tid];
#pragma unroll
        for (int r = 0; r < 8; r++) acc[r] = fmaf(rows[r][k], w, acc[r]);
    }
#pragma unroll
    for (int r = 0; r < 8; r++)
        h[(size_t)(r0 + r) * COUT + tid] = fmaxf(acc[r], 0.f);
}

// S_hat[b] = h_s[b] @ h_t[b]^T : [1024,256] x [1024,256]^T. 64x64 tile, 4x4/thread.
__global__ void shat_gemm(const float* __restrict__ hs, const float* __restrict__ ht,
                          float* __restrict__ Sh) {
    __shared__ float As[32][68];
    __shared__ float Bs[32][68];
    int b  = blockIdx.z;
    int s0 = blockIdx.y * 64, t0 = blockIdx.x * 64;
    const float* A  = hs + (size_t)b * NSEQ * COUT;
    const float* Bm = ht + (size_t)b * NSEQ * COUT;
    int tid = threadIdx.x;
    int tx = tid & 15, ty = tid >> 4;
    float acc[4][4] = {};
    for (int k0 = 0; k0 < COUT; k0 += 32) {
#pragma unroll
        for (int q = 0; q < 2; q++) {
            int lid = (tid << 1) + q;
            int row = lid >> 3, k4 = (lid & 7) << 2;
            float4 av = *(const float4*)(A + (size_t)(s0 + row) * COUT + k0 + k4);
            As[k4 + 0][row] = av.x; As[k4 + 1][row] = av.y;
            As[k4 + 2][row] = av.z; As[k4 + 3][row] = av.w;
            float4 bv = *(const float4*)(Bm + (size_t)(t0 + row) * COUT + k0 + k4);
            Bs[k4 + 0][row] = bv.x; Bs[k4 + 1][row] = bv.y;
            Bs[k4 + 2][row] = bv.z; Bs[k4 + 3][row] = bv.w;
        }
        __syncthreads();
#pragma unroll
        for (int k = 0; k < 32; k++) {
            float av[4], bv[4];
#pragma unroll
            for (int i = 0; i < 4; i++) av[i] = As[k][ty * 4 + i];
#pragma unroll
            for (int j = 0; j < 4; j++) bv[j] = Bs[k][tx * 4 + j];
#pragma unroll
            for (int i = 0; i < 4; i++)
#pragma unroll
                for (int j = 0; j < 4; j++)
                    acc[i][j] = fmaf(av[i], bv[j], acc[i][j]);
        }
        __syncthreads();
    }
#pragma unroll
    for (int i = 0; i < 4; i++) {
        float4 v = make_float4(acc[i][0], acc[i][1], acc[i][2], acc[i][3]);
        *(float4*)(Sh + ((size_t)b * NSEQ + s0 + ty * 4 + i) * NSEQ + t0 + tx * 4) = v;
    }
}

// Row softmax of Sh -> S; Sfin = init ? w*S : Sfin + w*S. One block per row.
__global__ void softmax_acc(const float* __restrict__ Sh, float* __restrict__ S,
                            float* __restrict__ Sfin, const float* __restrict__ sw,
                            int widx, int init) {
    int row = blockIdx.x, tid = threadIdx.x;
    float4 v = *(const float4*)(Sh + (size_t)row * NSEQ + tid * 4);
    float m = fmaxf(fmaxf(v.x, v.y), fmaxf(v.z, v.w));
#pragma unroll
    for (int o = 32; o; o >>= 1) m = fmaxf(m, __shfl_xor(m, o));
    __shared__ float redm[4], reds[4];
    int wid = tid >> 6, lane = tid & 63;
    if (lane == 0) redm[wid] = m;
    __syncthreads();
    m = fmaxf(fmaxf(redm[0], redm[1]), fmaxf(redm[2], redm[3]));
    float4 e;
    e.x = __expf(v.x - m); e.y = __expf(v.y - m);
    e.z = __expf(v.z - m); e.w = __expf(v.w - m);
    float s = e.x + e.y + e.z + e.w;
#pragma unroll
    for (int o = 32; o; o >>= 1) s += __shfl_xor(s, o);
    if (lane == 0) reds[wid] = s;
    __syncthreads();
    s = reds[0] + reds[1] + reds[2] + reds[3];
    float inv = 1.0f / s;
    float4 sv = make_float4(e.x * inv, e.y * inv, e.z * inv, e.w * inv);
    *(float4*)(S + (size_t)row * NSEQ + tid * 4) = sv;
    float w = sw[widx];
    float* fp = Sfin + (size_t)row * NSEQ + tid * 4;
    float4 f;
    if (init) {
        f = make_float4(w * sv.x, w * sv.y, w * sv.z, w * sv.w);
    } else {
        float4 old = *(const float4*)fp;
        f = make_float4(fmaf(w, sv.x, old.x), fmaf(w, sv.y, old.y),
                        fmaf(w, sv.z, old.z), fmaf(w, sv.w, old.w));
    }
    *(float4*)fp = f;
}

// Final: out = row softmax of Sfin.
__global__ void softmax_out(const float* __restrict__ Sf, float* __restrict__ out) {
    int row = blockIdx.x, tid = threadIdx.x;
    float4 v = *(const float4*)(Sf + (size_t)row * NSEQ + tid * 4);
    float m = fmaxf(fmaxf(v.x, v.y), fmaxf(v.z, v.w));
#pragma unroll
    for (int o = 32; o; o >>= 1) m = fmaxf(m, __shfl_xor(m, o));
    __shared__ float redm[4], reds[4];
    int wid = tid >> 6, lane = tid & 63;
    if (lane == 0) redm[wid] = m;
    __syncthreads();
    m = fmaxf(fmaxf(redm[0], redm[1]), fmaxf(redm[2], redm[3]));
    float4 e;
    e.x = __expf(v.x - m); e.y = __expf(v.y - m);
    e.z = __expf(v.z - m); e.w = __expf(v.w - m);
    float s = e.x + e.y + e.z + e.w;
#pragma unroll
    for (int o = 32; o; o >>= 1) s += __shfl_xor(s, o);
    if (lane == 0) reds[wid] = s;
    __syncthreads();
    s = reds[0] + reds[1] + reds[2] + reds[3];
    float inv = 1.0f / s;
    float4 sv = make_float4(e.x * inv, e.y * inv, e.z * inv, e.w * inv);
    *(float4*)(out + (size_t)row * NSEQ + tid * 4) = sv;
}

// r_t[b,t,:] += sum_s S[b,s,t] * r_s[b,s,:]   (S^T @ r_s), s-chunked with atomics.
__global__ void rt_gemm(const float* __restrict__ S, const float* __restrict__ rs,
                        float* __restrict__ rt) {
    __shared__ float St[64][68];
    __shared__ float Rt[64][36];
    int b = blockIdx.z, t0 = blockIdx.x * 64, sc0 = blockIdx.y * 256;
    int tid = threadIdx.x;
    int t = tid & 63, jg = tid >> 6;
    float acc[8] = {};
    for (int s0 = sc0; s0 < sc0 + 256; s0 += 64) {
#pragma unroll
        for (int p = 0; p < 4; p++) {
            int srow = (tid >> 4) + p * 16, t4 = (tid & 15) << 2;
            float4 v = *(const float4*)(S + ((size_t)b * NSEQ + s0 + srow) * NSEQ + t0 + t4);
            *(float4*)&St[srow][t4] = v;
        }
#pragma unroll
        for (int q = 0; q < 2; q++) {
            int lid = (tid << 1) + q;
            int srow = lid >> 3, j4 = (lid & 7) << 2;
            float4 v = *(const float4*)(rs + ((size_t)b * NSEQ + s0 + srow) * RDIM + j4);
            *(float4*)&Rt[srow][j4] = v;
        }
        __syncthreads();
        for (int s = 0; s < 64; s++) {
            float sv = St[s][t];
#pragma unroll
            for (int jj = 0; jj < 8; jj++)
                acc[jj] = fmaf(sv, Rt[s][jg * 8 + jj], acc[jj]);
        }
        __syncthreads();
    }
#pragma unroll
    for (int jj = 0; jj < 8; jj++)
        atomicAdd(&rt[((size_t)b * NSEQ + t0 + t) * RDIM + jg * 8 + jj], acc[jj]);
}

// o = relu(t_r @ Wp + bp);  P = o @ Wm1 (+ bm1 if add_bm1). 8 rows/block.
__global__ void psi_r(const float* __restrict__ t_r, const float* __restrict__ Wp,
                      const float* __restrict__ bp, const float* __restrict__ Wm1,
                      const float* __restrict__ bm1, float* __restrict__ P, int add_bm1) {
    __shared__ float sWp[32 * 32], sWm1[32 * 32];
    __shared__ float srow[8][33], so[8][33];
    int tid = threadIdx.x;
#pragma unroll
    for (int q = 0; q < 4; q++) {
        sWp[tid + q * 256]  = Wp[tid + q * 256];
        sWm1[tid + q * 256] = Wm1[tid + q * 256];
    }
    int g = tid >> 5, j = tid & 31;
    int row = blockIdx.x * 8 + g;
    srow[g][j] = t_r[(size_t)row * RDIM + j];
    __syncthreads();
    float acc = bp[j];
#pragma unroll
    for (int k = 0; k < 32; k++) acc = fmaf(srow[g][k], sWp[k * 32 + j], acc);
    float o = fmaxf(acc, 0.f);
    so[g][j] = o;
    __syncthreads();
    float acc2 = add_bm1 ? bm1[j] : 0.f;
#pragma unroll
    for (int k = 0; k < 32; k++) acc2 = fmaf(so[g][k], sWm1[k * 32 + j], acc2);
    P[(size_t)row * RDIM + j] = acc2;
}

// S_hat[b,s,t] += sum_k relu(Ps[b,s,k]-Pt[b,t,k])*Wm2[k] + bm2.  64x64 tile, 4x4/thread.
__global__ void upd_add(const float* __restrict__ Ps, const float* __restrict__ Pt,
                        const float* __restrict__ Wm2, const float* __restrict__ bm2p,
                        float* __restrict__ Sh) {
    __shared__ float sPs[64][33], sPt[64][33];
    __shared__ float swm[32];
    int b = blockIdx.z, s0 = blockIdx.y * 64, t0 = blockIdx.x * 64;
    int tid = threadIdx.x;
#pragma unroll
    for (int q = 0; q < 2; q++) {
        int lid = (tid << 1) + q, r = lid >> 3, c4 = (lid & 7) << 2;
        float4 a = *(const float4*)(Ps + ((size_t)b * NSEQ + s0 + r) * RDIM + c4);
        sPs[r][c4] = a.x; sPs[r][c4 + 1] = a.y; sPs[r][c4 + 2] = a.z; sPs[r][c4 + 3] = a.w;
        float4 c = *(const float4*)(Pt + ((size_t)b * NSEQ + t0 + r) * RDIM + c4);
        sPt[r][c4] = c.x; sPt[r][c4 + 1] = c.y; sPt[r][c4 + 2] = c.z; sPt[r][c4 + 3] = c.w;
    }
    if (tid < 32) swm[tid] = Wm2[tid];
    __syncthreads();
    float bm2 = bm2p[0];
    int tx = tid & 15, ty = tid >> 4;
    float acc[4][4] = {};
#pragma unroll
    for (int k = 0; k < 32; k++) {
        float w = swm[k];
        float ps[4], pt[4];
#pragma unroll
        for (int i = 0; i < 4; i++) ps[i] = sPs[ty * 4 + i][k];
#pragma unroll
        for (int j = 0; j < 4; j++) pt[j] = sPt[tx * 4 + j][k];
#pragma unroll
        for (int i = 0; i < 4; i++)
#pragma unroll
            for (int j = 0; j < 4; j++)
                acc[i][j] = fmaf(fmaxf(ps[i] - pt[j], 0.f), w, acc[i][j]);
    }
#pragma unroll
    for (int i = 0; i < 4; i++) {
        size_t base = ((size_t)b * NSEQ + s0 + ty * 4 + i) * NSEQ + t0 + tx * 4;
        float4 old = *(const float4*)(Sh + base);
        old.x += acc[i][0] + bm2; old.y += acc[i][1] + bm2;
        old.z += acc[i][2] + bm2; old.w += acc[i][3] + bm2;
        *(float4*)(Sh + base) = old;
    }
}

extern "C" void kernel_launch(void* const* d_in, const int* in_sizes, int n_in,
                              void* d_out, int out_size, void* d_ws, size_t ws_size,
                              hipStream_t stream) {
    const float* x_s  = (const float*)d_in[0];
    const int*   ei_s = (const int*)  d_in[1];
    const float* x_t  = (const float*)d_in[2];
    const int*   ei_t = (const int*)  d_in[3];
    const float* r    = (const float*)d_in[4];
    const float* W1   = (const float*)d_in[5];
    const float* b1   = (const float*)d_in[6];
    const float* Wp   = (const float*)d_in[7];
    const float* bp   = (const float*)d_in[8];
    const float* Wm1  = (const float*)d_in[9];
    const float* bm1  = (const float*)d_in[10];
    const float* Wm2  = (const float*)d_in[11];
    const float* bm2  = (const float*)d_in[12];
    const float* sw   = (const float*)d_in[13];
    float* out = (float*)d_out;

    float* ws = (float*)d_ws;
    float* t_s  = ws;  ws += (size_t)BNN * CIN;
    float* t_t  = ws;  ws += (size_t)BNN * CIN;
    float* h_s  = ws;  ws += (size_t)BNN * COUT;
    float* h_t  = ws;  ws += (size_t)BNN * COUT;
    float* Sh   = ws;  ws += (size_t)NBATCH * NSEQ * NSEQ;
    float* S    = ws;  ws += (size_t)NBATCH * NSEQ * NSEQ;
    float* Sfin = ws;  ws += (size_t)NBATCH * NSEQ * NSEQ;
    float* rt   = ws;  ws += (size_t)BNN * RDIM;
    float* trs  = ws;  ws += (size_t)BNN * RDIM;
    float* trt  = ws;  ws += (size_t)BNN * RDIM;
    float* Ps   = ws;  ws += (size_t)BNN * RDIM;
    float* Pt   = ws;  ws += (size_t)BNN * RDIM;

    // psi_1 for both graphs
    copy2_kernel<<<512, 256, 0, stream>>>(x_s, t_s, x_t, t_t);
    scatter128<<<8192, 256, 0, stream>>>(x_s, ei_s, t_s);
    scatter128<<<8192, 256, 0, stream>>>(x_t, ei_t, t_t);
    psi1_gemm<<<512, 256, 0, stream>>>(t_s, W1, b1, h_s);
    psi1_gemm<<<512, 256, 0, stream>>>(t_t, W1, b1, h_t);
    shat_gemm<<<dim3(16, 16, 4), 256, 0, stream>>>(h_s, h_t, Sh);

    for (int i = 0; i < 2; i++) {
        softmax_acc<<<4096, 256, 0, stream>>>(Sh, S, Sfin, sw, i, i == 0 ? 1 : 0);
        hipMemsetAsync(rt, 0, (size_t)BNN * RDIM * sizeof(float), stream);
        rt_gemm<<<dim3(16, 4, 4), 256, 0, stream>>>(S, r + (size_t)i * BNN * RDIM, rt);
        hipMemcpyAsync(trs, r + (size_t)i * BNN * RDIM, (size_t)BNN * RDIM * sizeof(float),
                       hipMemcpyDeviceToDevice, stream);
        hipMemcpyAsync(trt, rt, (size_t)BNN * RDIM * sizeof(float),
                       hipMemcpyDeviceToDevice, stream);
        scatter32<<<2048, 256, 0, stream>>>(r + (size_t)i * BNN * RDIM, ei_s, trs);
        scatter32<<<2048, 256, 0, stream>>>(rt, ei_t, trt);
        psi_r<<<512, 256, 0, stream>>>(trs, Wp + i * RDIM * RDIM, bp + i * RDIM,
                                       Wm1, bm1, Ps, 1);
        psi_r<<<512, 256, 0, stream>>>(trt, Wp + i * RDIM * RDIM, bp + i * RDIM,
                                       Wm1, bm1, Pt, 0);
        upd_add<<<dim3(16, 16, 4), 256, 0, stream>>>(Ps, Pt, Wm2, bm2, Sh);
    }
    softmax_acc<<<4096, 256, 0, stream>>>(Sh, S, Sfin, sw, 2, 0);
    softmax_out<<<4096, 256, 0, stream>>>(Sfin, out);
}

// Round 2
// 291.239 us; speedup vs baseline: 2.0067x; 2.0067x over previous
//
#include <hip/hip_runtime.h>
#include <hip/hip_bf16.h>

#define NBATCH 4
#define NSEQ   1024
#define BNN    4096
#define CIN    128
#define COUT   256
#define RDIM   32
#define NEDGE  65536

// ---------- edge bucketing (counting sort by dst) ----------
// cnt[2][BNN] must be zeroed before edge_hist.
__global__ void edge_hist(const int* __restrict__ ei_s, const int* __restrict__ ei_t,
                          int* __restrict__ cnt) {
    int gid = blockIdx.x * blockDim.x + threadIdx.x;   // 2*NEDGE
    int list = gid >> 16;
    int e = gid & (NEDGE - 1);
    const int* ei = list ? ei_t : ei_s;
    atomicAdd(&cnt[list * BNN + ei[NEDGE + e]], 1);
}

// One block per list. 256 threads x 16 counts each -> exclusive offsets + cursor.
__global__ void edge_scan(const int* __restrict__ cnt, int* __restrict__ offs,
                          int* __restrict__ cursor) {
    __shared__ int sums[256];
    int list = blockIdx.x;
    int tid = threadIdx.x;
    int local[16];
    int s = 0;
#pragma unroll
    for (int k = 0; k < 16; k++) { local[k] = cnt[list * BNN + tid * 16 + k]; s += local[k]; }
    sums[tid] = s;
    __syncthreads();
    for (int off = 1; off < 256; off <<= 1) {
        int v = 0;
        if (tid >= off) v = sums[tid - off];
        __syncthreads();
        if (tid >= off) sums[tid] += v;
        __syncthreads();
    }
    int run = tid ? sums[tid - 1] : 0;
#pragma unroll
    for (int k = 0; k < 16; k++) {
        offs[list * (BNN + 1) + tid * 16 + k] = run;
        cursor[list * BNN + tid * 16 + k] = run;
        run += local[k];
    }
    if (tid == 255) offs[list * (BNN + 1) + BNN] = run;
}

__global__ void edge_place(const int* __restrict__ ei_s, const int* __restrict__ ei_t,
                           int* __restrict__ cursor, int* __restrict__ ssrc) {
    int gid = blockIdx.x * blockDim.x + threadIdx.x;   // 2*NEDGE
    int list = gid >> 16;
    int e = gid & (NEDGE - 1);
    const int* ei = list ? ei_t : ei_s;
    int dst = ei[NEDGE + e], src = ei[e];
    int p = atomicAdd(&cursor[list * BNN + dst], 1);
    ssrc[list * NEDGE + p] = src;
}

// t[n] = x[n] + sum_{e: dst=n} x[src_e]   (128-wide). One block (128 thr) per node.
__global__ void gather_agg128(const float* __restrict__ x_s, const float* __restrict__ x_t,
                              const int* __restrict__ offs, const int* __restrict__ ssrc,
                              float* __restrict__ t_s, float* __restrict__ t_t) {
    int node = blockIdx.x & (BNN - 1);
    int list = blockIdx.x >> 12;
    const float* x = list ? x_t : x_s;
    float* t = list ? t_t : t_s;
    int c = threadIdx.x;
    int beg = offs[list * (BNN + 1) + node], end = offs[list * (BNN + 1) + node + 1];
    float acc = x[(size_t)node * CIN + c];
    for (int e = beg; e < end; e++)
        acc += x[(size_t)ssrc[list * NEDGE + e] * CIN + c];
    t[(size_t)node * CIN + c] = acc;
}

// 32-wide variant; blockIdx.y selects (rs->trs via list-s) or (rt->trt via list-t).
__global__ void gather_agg32(const float* __restrict__ rs, const float* __restrict__ rtin,
                             const int* __restrict__ offs, const int* __restrict__ ssrc,
                             float* __restrict__ trs, float* __restrict__ trt) {
    int list = blockIdx.y;
    int node = blockIdx.x * 8 + (threadIdx.x >> 5);
    int c = threadIdx.x & 31;
    const float* in = list ? rtin : rs;
    float* outp = list ? trt : trs;
    int beg = offs[list * (BNN + 1) + node], end = offs[list * (BNN + 1) + node + 1];
    float acc = in[(size_t)node * RDIM + c];
    for (int e = beg; e < end; e++)
        acc += in[(size_t)ssrc[list * NEDGE + e] * RDIM + c];
    outp[(size_t)node * RDIM + c] = acc;
}

// h = relu(t @ W1 + b1) : [4096,128] @ [128,256]. 8 rows per block, thread = out col.
__global__ void psi1_gemm(const float* __restrict__ t, const float* __restrict__ W1,
                          const float* __restrict__ b1, float* __restrict__ h) {
    __shared__ float rows[8][CIN];
    int r0 = blockIdx.x * 8;
    int tid = threadIdx.x;
    {
        int rr = tid >> 5, c4 = (tid & 31) << 2;
        *(float4*)&rows[rr][c4] = *(const float4*)(t + (size_t)(r0 + rr) * CIN + c4);
    }
    __syncthreads();
    float acc[8];
    float bias = b1[tid];
#pragma unroll
    for (int r = 0; r < 8; r++) acc[r] = bias;
    for (int k = 0; k < CIN; k++) {
        float w = W1[k * COUT + tid];
#pragma unroll
        for (int r = 0; r < 8; r++) acc[r] = fmaf(rows[r][k], w, acc[r]);
    }
#pragma unroll
    for (int r = 0; r < 8; r++)
        h[(size_t)(r0 + r) * COUT + tid] = fmaxf(acc[r], 0.f);
}

// S_hat[b] = h_s[b] @ h_t[b]^T : [1024,256] x [1024,256]^T. 64x64 tile, 4x4/thread.
__global__ void shat_gemm(const float* __restrict__ hs, const float* __restrict__ ht,
                          float* __restrict__ Sh) {
    __shared__ float As[32][68];
    __shared__ float Bs[32][68];
    int b  = blockIdx.z;
    int s0 = blockIdx.y * 64, t0 = blockIdx.x * 64;
    const float* A  = hs + (size_t)b * NSEQ * COUT;
    const float* Bm = ht + (size_t)b * NSEQ * COUT;
    int tid = threadIdx.x;
    int tx = tid & 15, ty = tid >> 4;
    float acc[4][4] = {};
    for (int k0 = 0; k0 < COUT; k0 += 32) {
#pragma unroll
        for (int q = 0; q < 2; q++) {
            int lid = (tid << 1) + q;
            int row = lid >> 3, k4 = (lid & 7) << 2;
            float4 av = *(const float4*)(A + (size_t)(s0 + row) * COUT + k0 + k4);
            As[k4 + 0][row] = av.x; As[k4 + 1][row] = av.y;
            As[k4 + 2][row] = av.z; As[k4 + 3][row] = av.w;
            float4 bv = *(const float4*)(Bm + (size_t)(t0 + row) * COUT + k0 + k4);
            Bs[k4 + 0][row] = bv.x; Bs[k4 + 1][row] = bv.y;
            Bs[k4 + 2][row] = bv.z; Bs[k4 + 3][row] = bv.w;
        }
        __syncthreads();
#pragma unroll
        for (int k = 0; k < 32; k++) {
            float av[4], bv[4];
#pragma unroll
            for (int i = 0; i < 4; i++) av[i] = As[k][ty * 4 + i];
#pragma unroll
            for (int j = 0; j < 4; j++) bv[j] = Bs[k][tx * 4 + j];
#pragma unroll
            for (int i = 0; i < 4; i++)
#pragma unroll
                for (int j = 0; j < 4; j++)
                    acc[i][j] = fmaf(av[i], bv[j], acc[i][j]);
        }
        __syncthreads();
    }
#pragma unroll
    for (int i = 0; i < 4; i++) {
        float4 v = make_float4(acc[i][0], acc[i][1], acc[i][2], acc[i][3]);
        *(float4*)(Sh + ((size_t)b * NSEQ + s0 + ty * 4 + i) * NSEQ + t0 + tx * 4) = v;
    }
}

// Row softmax of Sh -> S; Sfin = init ? w*S : Sfin + w*S. One block per row.
__global__ void softmax_acc(const float* __restrict__ Sh, float* __restrict__ S,
                            float* __restrict__ Sfin, const float* __restrict__ sw,
                            int widx, int init) {
    int row = blockIdx.x, tid = threadIdx.x;
    float4 v = *(const float4*)(Sh + (size_t)row * NSEQ + tid * 4);
    float m = fmaxf(fmaxf(v.x, v.y), fmaxf(v.z, v.w));
#pragma unroll
    for (int o = 32; o; o >>= 1) m = fmaxf(m, __shfl_xor(m, o));
    __shared__ float redm[4], reds[4];
    int wid = tid >> 6, lane = tid & 63;
    if (lane == 0) redm[wid] = m;
    __syncthreads();
    m = fmaxf(fmaxf(redm[0], redm[1]), fmaxf(redm[2], redm[3]));
    float4 e;
    e.x = __expf(v.x - m); e.y = __expf(v.y - m);
    e.z = __expf(v.z - m); e.w = __expf(v.w - m);
    float s = e.x + e.y + e.z + e.w;
#pragma unroll
    for (int o = 32; o; o >>= 1) s += __shfl_xor(s, o);
    if (lane == 0) reds[wid] = s;
    __syncthreads();
    s = reds[0] + reds[1] + reds[2] + reds[3];
    float inv = 1.0f / s;
    float4 sv = make_float4(e.x * inv, e.y * inv, e.z * inv, e.w * inv);
    *(float4*)(S + (size_t)row * NSEQ + tid * 4) = sv;
    float w = sw[widx];
    float* fp = Sfin + (size_t)row * NSEQ + tid * 4;
    float4 f;
    if (init) {
        f = make_float4(w * sv.x, w * sv.y, w * sv.z, w * sv.w);
    } else {
        float4 old = *(const float4*)fp;
        f = make_float4(fmaf(w, sv.x, old.x), fmaf(w, sv.y, old.y),
                        fmaf(w, sv.z, old.z), fmaf(w, sv.w, old.w));
    }
    *(float4*)fp = f;
}

// Final: out = row softmax of Sfin.
__global__ void softmax_out(const float* __restrict__ Sf, float* __restrict__ out) {
    int row = blockIdx.x, tid = threadIdx.x;
    float4 v = *(const float4*)(Sf + (size_t)row * NSEQ + tid * 4);
    float m = fmaxf(fmaxf(v.x, v.y), fmaxf(v.z, v.w));
#pragma unroll
    for (int o = 32; o; o >>= 1) m = fmaxf(m, __shfl_xor(m, o));
    __shared__ float redm[4], reds[4];
    int wid = tid >> 6, lane = tid & 63;
    if (lane == 0) redm[wid] = m;
    __syncthreads();
    m = fmaxf(fmaxf(redm[0], redm[1]), fmaxf(redm[2], redm[3]));
    float4 e;
    e.x = __expf(v.x - m); e.y = __expf(v.y - m);
    e.z = __expf(v.z - m); e.w = __expf(v.w - m);
    float s = e.x + e.y + e.z + e.w;
#pragma unroll
    for (int o = 32; o; o >>= 1) s += __shfl_xor(s, o);
    if (lane == 0) reds[wid] = s;
    __syncthreads();
    s = reds[0] + reds[1] + reds[2] + reds[3];
    float inv = 1.0f / s;
    float4 sv = make_float4(e.x * inv, e.y * inv, e.z * inv, e.w * inv);
    *(float4*)(out + (size_t)row * NSEQ + tid * 4) = sv;
}

// r_t[b,t,:] += sum_s S[b,s,t] * r_s[b,s,:]   (S^T @ r_s), s-chunked with atomics.
__global__ void rt_gemm(const float* __restrict__ S, const float* __restrict__ rs,
                        float* __restrict__ rt) {
    __shared__ float St[64][68];
    __shared__ float Rt[64][36];
    int b = blockIdx.z, t0 = blockIdx.x * 64, sc0 = blockIdx.y * 256;
    int tid = threadIdx.x;
    int t = tid & 63, jg = tid >> 6;
    float acc[8] = {};
    for (int s0 = sc0; s0 < sc0 + 256; s0 += 64) {
#pragma unroll
        for (int p = 0; p < 4; p++) {
            int srow = (tid >> 4) + p * 16, t4 = (tid & 15) << 2;
            float4 v = *(const float4*)(S + ((size_t)b * NSEQ + s0 + srow) * NSEQ + t0 + t4);
            *(float4*)&St[srow][t4] = v;
        }
#pragma unroll
        for (int q = 0; q < 2; q++) {
            int lid = (tid << 1) + q;
            int srow = lid >> 3, j4 = (lid & 7) << 2;
            float4 v = *(const float4*)(rs + ((size_t)b * NSEQ + s0 + srow) * RDIM + j4);
            *(float4*)&Rt[srow][j4] = v;
        }
        __syncthreads();
        for (int s = 0; s < 64; s++) {
            float sv = St[s][t];
#pragma unroll
            for (int jj = 0; jj < 8; jj++)
                acc[jj] = fmaf(sv, Rt[s][jg * 8 + jj], acc[jj]);
        }
        __syncthreads();
    }
#pragma unroll
    for (int jj = 0; jj < 8; jj++)
        atomicAdd(&rt[((size_t)b * NSEQ + t0 + t) * RDIM + jg * 8 + jj], acc[jj]);
}

// o = relu(t_r @ Wp + bp);  P = o @ Wm1 (+ bm1 if add_bm1). 8 rows/block.
__global__ void psi_r(const float* __restrict__ t_r, const float* __restrict__ Wp,
                      const float* __restrict__ bp, const float* __restrict__ Wm1,
                      const float* __restrict__ bm1, float* __restrict__ P, int add_bm1) {
    __shared__ float sWp[32 * 32], sWm1[32 * 32];
    __shared__ float srow[8][33], so[8][33];
    int tid = threadIdx.x;
#pragma unroll
    for (int q = 0; q < 4; q++) {
        sWp[tid + q * 256]  = Wp[tid + q * 256];
        sWm1[tid + q * 256] = Wm1[tid + q * 256];
    }
    int g = tid >> 5, j = tid & 31;
    int row = blockIdx.x * 8 + g;
    srow[g][j] = t_r[(size_t)row * RDIM + j];
    __syncthreads();
    float acc = bp[j];
#pragma unroll
    for (int k = 0; k < 32; k++) acc = fmaf(srow[g][k], sWp[k * 32 + j], acc);
    float o = fmaxf(acc, 0.f);
    so[g][j] = o;
    __syncthreads();
    float acc2 = add_bm1 ? bm1[j] : 0.f;
#pragma unroll
    for (int k = 0; k < 32; k++) acc2 = fmaf(so[g][k], sWm1[k * 32 + j], acc2);
    P[(size_t)row * RDIM + j] = acc2;
}

// S_hat[b,s,t] += sum_k relu(Ps[b,s,k]-Pt[b,t,k])*Wm2[k] + bm2.  64x64 tile, 4x4/thread.
__global__ void upd_add(const float* __restrict__ Ps, const float* __restrict__ Pt,
                        const float* __restrict__ Wm2, const float* __restrict__ bm2p,
                        float* __restrict__ Sh) {
    __shared__ float sPs[64][33], sPt[64][33];
    __shared__ float swm[32];
    int b = blockIdx.z, s0 = blockIdx.y * 64, t0 = blockIdx.x * 64;
    int tid = threadIdx.x;
#pragma unroll
    for (int q = 0; q < 2; q++) {
        int lid = (tid << 1) + q, r = lid >> 3, c4 = (lid & 7) << 2;
        float4 a = *(const float4*)(Ps + ((size_t)b * NSEQ + s0 + r) * RDIM + c4);
        sPs[r][c4] = a.x; sPs[r][c4 + 1] = a.y; sPs[r][c4 + 2] = a.z; sPs[r][c4 + 3] = a.w;
        float4 c = *(const float4*)(Pt + ((size_t)b * NSEQ + t0 + r) * RDIM + c4);
        sPt[r][c4] = c.x; sPt[r][c4 + 1] = c.y; sPt[r][c4 + 2] = c.z; sPt[r][c4 + 3] = c.w;
    }
    if (tid < 32) swm[tid] = Wm2[tid];
    __syncthreads();
    float bm2 = bm2p[0];
    int tx = tid & 15, ty = tid >> 4;
    float acc[4][4] = {};
#pragma unroll
    for (int k = 0; k < 32; k++) {
        float w = swm[k];
        float ps[4], pt[4];
#pragma unroll
        for (int i = 0; i < 4; i++) ps[i] = sPs[ty * 4 + i][k];
#pragma unroll
        for (int j = 0; j < 4; j++) pt[j] = sPt[tx * 4 + j][k];
#pragma unroll
        for (int i = 0; i < 4; i++)
#pragma unroll
            for (int j = 0; j < 4; j++)
                acc[i][j] = fmaf(fmaxf(ps[i] - pt[j], 0.f), w, acc[i][j]);
    }
#pragma unroll
    for (int i = 0; i < 4; i++) {
        size_t base = ((size_t)b * NSEQ + s0 + ty * 4 + i) * NSEQ + t0 + tx * 4;
        float4 old = *(const float4*)(Sh + base);
        old.x += acc[i][0] + bm2; old.y += acc[i][1] + bm2;
        old.z += acc[i][2] + bm2; old.w += acc[i][3] + bm2;
        *(float4*)(Sh + base) = old;
    }
}

extern "C" void kernel_launch(void* const* d_in, const int* in_sizes, int n_in,
                              void* d_out, int out_size, void* d_ws, size_t ws_size,
                              hipStream_t stream) {
    const float* x_s  = (const float*)d_in[0];
    const int*   ei_s = (const int*)  d_in[1];
    const float* x_t  = (const float*)d_in[2];
    const int*   ei_t = (const int*)  d_in[3];
    const float* r    = (const float*)d_in[4];
    const float* W1   = (const float*)d_in[5];
    const float* b1   = (const float*)d_in[6];
    const float* Wp   = (const float*)d_in[7];
    const float* bp   = (const float*)d_in[8];
    const float* Wm1  = (const float*)d_in[9];
    const float* bm1  = (const float*)d_in[10];
    const float* Wm2  = (const float*)d_in[11];
    const float* bm2  = (const float*)d_in[12];
    const float* sw   = (const float*)d_in[13];
    float* out = (float*)d_out;

    float* ws = (float*)d_ws;
    float* t_s  = ws;  ws += (size_t)BNN * CIN;
    float* t_t  = ws;  ws += (size_t)BNN * CIN;
    float* h_s  = ws;  ws += (size_t)BNN * COUT;
    float* h_t  = ws;  ws += (size_t)BNN * COUT;
    float* Sh   = ws;  ws += (size_t)NBATCH * NSEQ * NSEQ;
    float* S    = ws;  ws += (size_t)NBATCH * NSEQ * NSEQ;
    float* Sfin = ws;  ws += (size_t)NBATCH * NSEQ * NSEQ;
    float* rt   = ws;  ws += (size_t)BNN * RDIM;
    float* trs  = ws;  ws += (size_t)BNN * RDIM;
    float* trt  = ws;  ws += (size_t)BNN * RDIM;
    float* Ps   = ws;  ws += (size_t)BNN * RDIM;
    float* Pt   = ws;  ws += (size_t)BNN * RDIM;
    int* icnt  = (int*)ws;
    int* ioffs = icnt  + 2 * BNN;
    int* icur  = ioffs + 2 * (BNN + 1);
    int* issrc = icur  + 2 * BNN;   // 2*NEDGE ints

    // ---- bucket edges by dst (both lists) ----
    hipMemsetAsync(icnt, 0, 2 * BNN * sizeof(int), stream);
    edge_hist <<<512, 256, 0, stream>>>(ei_s, ei_t, icnt);
    edge_scan <<<2, 256, 0, stream>>>(icnt, ioffs, icur);
    edge_place<<<512, 256, 0, stream>>>(ei_s, ei_t, icur, issrc);

    // ---- psi_1 for both graphs (gather form, no float atomics) ----
    gather_agg128<<<8192, 128, 0, stream>>>(x_s, x_t, ioffs, issrc, t_s, t_t);
    psi1_gemm<<<512, 256, 0, stream>>>(t_s, W1, b1, h_s);
    psi1_gemm<<<512, 256, 0, stream>>>(t_t, W1, b1, h_t);
    shat_gemm<<<dim3(16, 16, 4), 256, 0, stream>>>(h_s, h_t, Sh);

    for (int i = 0; i < 2; i++) {
        softmax_acc<<<4096, 256, 0, stream>>>(Sh, S, Sfin, sw, i, i == 0 ? 1 : 0);
        hipMemsetAsync(rt, 0, (size_t)BNN * RDIM * sizeof(float), stream);
        rt_gemm<<<dim3(16, 4, 4), 256, 0, stream>>>(S, r + (size_t)i * BNN * RDIM, rt);
        gather_agg32<<<dim3(512, 2), 256, 0, stream>>>(r + (size_t)i * BNN * RDIM, rt,
                                                       ioffs, issrc, trs, trt);
        psi_r<<<512, 256, 0, stream>>>(trs, Wp + i * RDIM * RDIM, bp + i * RDIM,
                                       Wm1, bm1, Ps, 1);
        psi_r<<<512, 256, 0, stream>>>(trt, Wp + i * RDIM * RDIM, bp + i * RDIM,
                                       Wm1, bm1, Pt, 0);
        upd_add<<<dim3(16, 16, 4), 256, 0, stream>>>(Ps, Pt, Wm2, bm2, Sh);
    }
    softmax_acc<<<4096, 256, 0, stream>>>(Sh, S, Sfin, sw, 2, 0);
    softmax_out<<<4096, 256, 0, stream>>>(Sfin, out);
}

// Round 3
// 246.557 us; speedup vs baseline: 2.3703x; 1.1812x over previous
//
#include <hip/hip_runtime.h>
#include <hip/hip_bf16.h>

#define NBATCH 4
#define NSEQ   1024
#define BNN    4096
#define CIN    128
#define COUT   256
#define RDIM   32
#define NEDGE  65536

// ---------- edge bucketing (counting sort by dst) ----------
// cnt[2][BNN] must be zeroed before edge_hist.
__global__ void edge_hist(const int* __restrict__ ei_s, const int* __restrict__ ei_t,
                          int* __restrict__ cnt) {
    int gid = blockIdx.x * blockDim.x + threadIdx.x;   // 2*NEDGE
    int list = gid >> 16;
    int e = gid & (NEDGE - 1);
    const int* ei = list ? ei_t : ei_s;
    atomicAdd(&cnt[list * BNN + ei[NEDGE + e]], 1);
}

// One block per list. 256 threads x 16 counts each -> exclusive offsets + cursor.
__global__ void edge_scan(const int* __restrict__ cnt, int* __restrict__ offs,
                          int* __restrict__ cursor) {
    __shared__ int sums[256];
    int list = blockIdx.x;
    int tid = threadIdx.x;
    int local[16];
    int s = 0;
#pragma unroll
    for (int k = 0; k < 16; k++) { local[k] = cnt[list * BNN + tid * 16 + k]; s += local[k]; }
    sums[tid] = s;
    __syncthreads();
    for (int off = 1; off < 256; off <<= 1) {
        int v = 0;
        if (tid >= off) v = sums[tid - off];
        __syncthreads();
        if (tid >= off) sums[tid] += v;
        __syncthreads();
    }
    int run = tid ? sums[tid - 1] : 0;
#pragma unroll
    for (int k = 0; k < 16; k++) {
        offs[list * (BNN + 1) + tid * 16 + k] = run;
        cursor[list * BNN + tid * 16 + k] = run;
        run += local[k];
    }
    if (tid == 255) offs[list * (BNN + 1) + BNN] = run;
}

__global__ void edge_place(const int* __restrict__ ei_s, const int* __restrict__ ei_t,
                           int* __restrict__ cursor, int* __restrict__ ssrc) {
    int gid = blockIdx.x * blockDim.x + threadIdx.x;   // 2*NEDGE
    int list = gid >> 16;
    int e = gid & (NEDGE - 1);
    const int* ei = list ? ei_t : ei_s;
    int dst = ei[NEDGE + e], src = ei[e];
    int p = atomicAdd(&cursor[list * BNN + dst], 1);
    ssrc[list * NEDGE + p] = src;
}

// t[n] = x[n] + sum_{e: dst=n} x[src_e]   (128-wide). One block (128 thr) per node.
__global__ void gather_agg128(const float* __restrict__ x_s, const float* __restrict__ x_t,
                              const int* __restrict__ offs, const int* __restrict__ ssrc,
                              float* __restrict__ t_s, float* __restrict__ t_t) {
    int node = blockIdx.x & (BNN - 1);
    int list = blockIdx.x >> 12;
    const float* x = list ? x_t : x_s;
    float* t = list ? t_t : t_s;
    int c = threadIdx.x;
    int beg = offs[list * (BNN + 1) + node], end = offs[list * (BNN + 1) + node + 1];
    float acc = x[(size_t)node * CIN + c];
    for (int e = beg; e < end; e++)
        acc += x[(size_t)ssrc[list * NEDGE + e] * CIN + c];
    t[(size_t)node * CIN + c] = acc;
}

// 32-wide variant; blockIdx.y selects (rs->trs via list-s) or (rt->trt via list-t).
__global__ void gather_agg32(const float* __restrict__ rs, const float* __restrict__ rtin,
                             const int* __restrict__ offs, const int* __restrict__ ssrc,
                             float* __restrict__ trs, float* __restrict__ trt) {
    int list = blockIdx.y;
    int node = blockIdx.x * 8 + (threadIdx.x >> 5);
    int c = threadIdx.x & 31;
    const float* in = list ? rtin : rs;
    float* outp = list ? trt : trs;
    int beg = offs[list * (BNN + 1) + node], end = offs[list * (BNN + 1) + node + 1];
    float acc = in[(size_t)node * RDIM + c];
    for (int e = beg; e < end; e++)
        acc += in[(size_t)ssrc[list * NEDGE + e] * RDIM + c];
    outp[(size_t)node * RDIM + c] = acc;
}

// h = relu(t @ W1 + b1) : [4096,128] @ [128,256]. 8 rows per block, thread = out col.
__global__ void psi1_gemm(const float* __restrict__ t, const float* __restrict__ W1,
                          const float* __restrict__ b1, float* __restrict__ h) {
    __shared__ float rows[8][CIN];
    int r0 = blockIdx.x * 8;
    int tid = threadIdx.x;
    {
        int rr = tid >> 5, c4 = (tid & 31) << 2;
        *(float4*)&rows[rr][c4] = *(const float4*)(t + (size_t)(r0 + rr) * CIN + c4);
    }
    __syncthreads();
    float acc[8];
    float bias = b1[tid];
#pragma unroll
    for (int r = 0; r < 8; r++) acc[r] = bias;
    for (int k = 0; k < CIN; k++) {
        float w = W1[k * COUT + tid];
#pragma unroll
        for (int r = 0; r < 8; r++) acc[r] = fmaf(rows[r][k], w, acc[r]);
    }
#pragma unroll
    for (int r = 0; r < 8; r++)
        h[(size_t)(r0 + r) * COUT + tid] = fmaxf(acc[r], 0.f);
}

// S_hat[b] = h_s[b] @ h_t[b]^T : [1024,256] x [1024,256]^T. 64x64 tile, 4x4/thread.
__global__ void shat_gemm(const float* __restrict__ hs, const float* __restrict__ ht,
                          float* __restrict__ Sh) {
    __shared__ float As[32][68];
    __shared__ float Bs[32][68];
    int b  = blockIdx.z;
    int s0 = blockIdx.y * 64, t0 = blockIdx.x * 64;
    const float* A  = hs + (size_t)b * NSEQ * COUT;
    const float* Bm = ht + (size_t)b * NSEQ * COUT;
    int tid = threadIdx.x;
    int tx = tid & 15, ty = tid >> 4;
    float acc[4][4] = {};
    for (int k0 = 0; k0 < COUT; k0 += 32) {
#pragma unroll
        for (int q = 0; q < 2; q++) {
            int lid = (tid << 1) + q;
            int row = lid >> 3, k4 = (lid & 7) << 2;
            float4 av = *(const float4*)(A + (size_t)(s0 + row) * COUT + k0 + k4);
            As[k4 + 0][row] = av.x; As[k4 + 1][row] = av.y;
            As[k4 + 2][row] = av.z; As[k4 + 3][row] = av.w;
            float4 bv = *(const float4*)(Bm + (size_t)(t0 + row) * COUT + k0 + k4);
            Bs[k4 + 0][row] = bv.x; Bs[k4 + 1][row] = bv.y;
            Bs[k4 + 2][row] = bv.z; Bs[k4 + 3][row] = bv.w;
        }
        __syncthreads();
#pragma unroll
        for (int k = 0; k < 32; k++) {
            float av[4], bv[4];
#pragma unroll
            for (int i = 0; i < 4; i++) av[i] = As[k][ty * 4 + i];
#pragma unroll
            for (int j = 0; j < 4; j++) bv[j] = Bs[k][tx * 4 + j];
#pragma unroll
            for (int i = 0; i < 4; i++)
#pragma unroll
                for (int j = 0; j < 4; j++)
                    acc[i][j] = fmaf(av[i], bv[j], acc[i][j]);
        }
        __syncthreads();
    }
#pragma unroll
    for (int i = 0; i < 4; i++) {
        float4 v = make_float4(acc[i][0], acc[i][1], acc[i][2], acc[i][3]);
        *(float4*)(Sh + ((size_t)b * NSEQ + s0 + ty * 4 + i) * NSEQ + t0 + tx * 4) = v;
    }
}

// Row softmax of Sh -> S; Sfin = init ? w*S : Sfin + w*S. One block per row.
__global__ void softmax_acc(const float* __restrict__ Sh, float* __restrict__ S,
                            float* __restrict__ Sfin, const float* __restrict__ sw,
                            int widx, int init) {
    int row = blockIdx.x, tid = threadIdx.x;
    float4 v = *(const float4*)(Sh + (size_t)row * NSEQ + tid * 4);
    float m = fmaxf(fmaxf(v.x, v.y), fmaxf(v.z, v.w));
#pragma unroll
    for (int o = 32; o; o >>= 1) m = fmaxf(m, __shfl_xor(m, o));
    __shared__ float redm[4], reds[4];
    int wid = tid >> 6, lane = tid & 63;
    if (lane == 0) redm[wid] = m;
    __syncthreads();
    m = fmaxf(fmaxf(redm[0], redm[1]), fmaxf(redm[2], redm[3]));
    float4 e;
    e.x = __expf(v.x - m); e.y = __expf(v.y - m);
    e.z = __expf(v.z - m); e.w = __expf(v.w - m);
    float s = e.x + e.y + e.z + e.w;
#pragma unroll
    for (int o = 32; o; o >>= 1) s += __shfl_xor(s, o);
    if (lane == 0) reds[wid] = s;
    __syncthreads();
    s = reds[0] + reds[1] + reds[2] + reds[3];
    float inv = 1.0f / s;
    float4 sv = make_float4(e.x * inv, e.y * inv, e.z * inv, e.w * inv);
    *(float4*)(S + (size_t)row * NSEQ + tid * 4) = sv;
    float w = sw[widx];
    float* fp = Sfin + (size_t)row * NSEQ + tid * 4;
    float4 f;
    if (init) {
        f = make_float4(w * sv.x, w * sv.y, w * sv.z, w * sv.w);
    } else {
        float4 old = *(const float4*)fp;
        f = make_float4(fmaf(w, sv.x, old.x), fmaf(w, sv.y, old.y),
                        fmaf(w, sv.z, old.z), fmaf(w, sv.w, old.w));
    }
    *(float4*)fp = f;
}

// Final: out = row softmax of Sfin.
__global__ void softmax_out(const float* __restrict__ Sf, float* __restrict__ out) {
    int row = blockIdx.x, tid = threadIdx.x;
    float4 v = *(const float4*)(Sf + (size_t)row * NSEQ + tid * 4);
    float m = fmaxf(fmaxf(v.x, v.y), fmaxf(v.z, v.w));
#pragma unroll
    for (int o = 32; o; o >>= 1) m = fmaxf(m, __shfl_xor(m, o));
    __shared__ float redm[4], reds[4];
    int wid = tid >> 6, lane = tid & 63;
    if (lane == 0) redm[wid] = m;
    __syncthreads();
    m = fmaxf(fmaxf(redm[0], redm[1]), fmaxf(redm[2], redm[3]));
    float4 e;
    e.x = __expf(v.x - m); e.y = __expf(v.y - m);
    e.z = __expf(v.z - m); e.w = __expf(v.w - m);
    float s = e.x + e.y + e.z + e.w;
#pragma unroll
    for (int o = 32; o; o >>= 1) s += __shfl_xor(s, o);
    if (lane == 0) reds[wid] = s;
    __syncthreads();
    s = reds[0] + reds[1] + reds[2] + reds[3];
    float inv = 1.0f / s;
    float4 sv = make_float4(e.x * inv, e.y * inv, e.z * inv, e.w * inv);
    *(float4*)(out + (size_t)row * NSEQ + tid * 4) = sv;
}

// rt partials: part[chunk][b*NSEQ+t][j] = sum_{s in chunk} S[b,s,t]*rs[b,s,j].
// Block: (s-chunk of 64, t-tile of 128, batch); 256 thr = 128 t x 2 j-halves.
__global__ void rt_part(const float* __restrict__ S, const float* __restrict__ rs,
                        float* __restrict__ part) {
    __shared__ float rsld[64][33];
    int b = blockIdx.z, t0 = blockIdx.y * 128, s0 = blockIdx.x * 64;
    int tid = threadIdx.x;
#pragma unroll
    for (int q = 0; q < 2; q++) {
        int lid = (tid << 1) + q;
        int row = lid >> 3, c4 = (lid & 7) << 2;
        float4 v = *(const float4*)(rs + ((size_t)b * NSEQ + s0 + row) * RDIM + c4);
        rsld[row][c4] = v.x; rsld[row][c4 + 1] = v.y;
        rsld[row][c4 + 2] = v.z; rsld[row][c4 + 3] = v.w;
    }
    __syncthreads();
    int t = t0 + (tid & 127);
    int j0 = (tid >> 7) << 4;
    float acc[16] = {};
    const float* Sp = S + ((size_t)b * NSEQ + s0) * NSEQ + t;
#pragma unroll 8
    for (int s = 0; s < 64; s++) {
        float sv = Sp[(size_t)s * NSEQ];
#pragma unroll
        for (int j = 0; j < 16; j++) acc[j] = fmaf(sv, rsld[s][j0 + j], acc[j]);
    }
    float* pp = part + (((size_t)blockIdx.x * NBATCH + b) * NSEQ + t) * RDIM + j0;
#pragma unroll
    for (int j4 = 0; j4 < 16; j4 += 4)
        *(float4*)(pp + j4) = make_float4(acc[j4], acc[j4 + 1], acc[j4 + 2], acc[j4 + 3]);
}

// rt[i4] = sum over 16 chunks of part[c][i4]  (float4 granularity).
__global__ void rt_reduce(const float* __restrict__ part, float* __restrict__ rt) {
    int i = blockIdx.x * blockDim.x + threadIdx.x;   // 32768 float4
    const float4* p = (const float4*)part + i;
    float4 a = make_float4(0.f, 0.f, 0.f, 0.f);
#pragma unroll
    for (int c = 0; c < 16; c++) {
        float4 v = p[(size_t)c * (BNN * RDIM / 4)];
        a.x += v.x; a.y += v.y; a.z += v.z; a.w += v.w;
    }
    ((float4*)rt)[i] = a;
}

// o = relu(t_r @ Wp + bp);  P = o @ Wm1 (+ bm1 if add_bm1). 8 rows/block.
__global__ void psi_r(const float* __restrict__ t_r, const float* __restrict__ Wp,
                      const float* __restrict__ bp, const float* __restrict__ Wm1,
                      const float* __restrict__ bm1, float* __restrict__ P, int add_bm1) {
    __shared__ float sWp[32 * 32], sWm1[32 * 32];
    __shared__ float srow[8][33], so[8][33];
    int tid = threadIdx.x;
#pragma unroll
    for (int q = 0; q < 4; q++) {
        sWp[tid + q * 256]  = Wp[tid + q * 256];
        sWm1[tid + q * 256] = Wm1[tid + q * 256];
    }
    int g = tid >> 5, j = tid & 31;
    int row = blockIdx.x * 8 + g;
    srow[g][j] = t_r[(size_t)row * RDIM + j];
    __syncthreads();
    float acc = bp[j];
#pragma unroll
    for (int k = 0; k < 32; k++) acc = fmaf(srow[g][k], sWp[k * 32 + j], acc);
    float o = fmaxf(acc, 0.f);
    so[g][j] = o;
    __syncthreads();
    float acc2 = add_bm1 ? bm1[j] : 0.f;
#pragma unroll
    for (int k = 0; k < 32; k++) acc2 = fmaf(so[g][k], sWm1[k * 32 + j], acc2);
    P[(size_t)row * RDIM + j] = acc2;
}

// S_hat[b,s,t] += sum_k relu(Ps[b,s,k]-Pt[b,t,k])*Wm2[k] + bm2.  64x64 tile, 4x4/thread.
__global__ void upd_add(const float* __restrict__ Ps, const float* __restrict__ Pt,
                        const float* __restrict__ Wm2, const float* __restrict__ bm2p,
                        float* __restrict__ Sh) {
    __shared__ float sPs[64][33], sPt[64][33];
    __shared__ float swm[32];
    int b = blockIdx.z, s0 = blockIdx.y * 64, t0 = blockIdx.x * 64;
    int tid = threadIdx.x;
#pragma unroll
    for (int q = 0; q < 2; q++) {
        int lid = (tid << 1) + q, r = lid >> 3, c4 = (lid & 7) << 2;
        float4 a = *(const float4*)(Ps + ((size_t)b * NSEQ + s0 + r) * RDIM + c4);
        sPs[r][c4] = a.x; sPs[r][c4 + 1] = a.y; sPs[r][c4 + 2] = a.z; sPs[r][c4 + 3] = a.w;
        float4 c = *(const float4*)(Pt + ((size_t)b * NSEQ + t0 + r) * RDIM + c4);
        sPt[r][c4] = c.x; sPt[r][c4 + 1] = c.y; sPt[r][c4 + 2] = c.z; sPt[r][c4 + 3] = c.w;
    }
    if (tid < 32) swm[tid] = Wm2[tid];
    __syncthreads();
    float bm2 = bm2p[0];
    int tx = tid & 15, ty = tid >> 4;
    float acc[4][4] = {};
#pragma unroll
    for (int k = 0; k < 32; k++) {
        float w = swm[k];
        float ps[4], pt[4];
#pragma unroll
        for (int i = 0; i < 4; i++) ps[i] = sPs[ty * 4 + i][k];
#pragma unroll
        for (int j = 0; j < 4; j++) pt[j] = sPt[tx * 4 + j][k];
#pragma unroll
        for (int i = 0; i < 4; i++)
#pragma unroll
            for (int j = 0; j < 4; j++)
                acc[i][j] = fmaf(fmaxf(ps[i] - pt[j], 0.f), w, acc[i][j]);
    }
#pragma unroll
    for (int i = 0; i < 4; i++) {
        size_t base = ((size_t)b * NSEQ + s0 + ty * 4 + i) * NSEQ + t0 + tx * 4;
        float4 old = *(const float4*)(Sh + base);
        old.x += acc[i][0] + bm2; old.y += acc[i][1] + bm2;
        old.z += acc[i][2] + bm2; old.w += acc[i][3] + bm2;
        *(float4*)(Sh + base) = old;
    }
}

extern "C" void kernel_launch(void* const* d_in, const int* in_sizes, int n_in,
                              void* d_out, int out_size, void* d_ws, size_t ws_size,
                              hipStream_t stream) {
    const float* x_s  = (const float*)d_in[0];
    const int*   ei_s = (const int*)  d_in[1];
    const float* x_t  = (const float*)d_in[2];
    const int*   ei_t = (const int*)  d_in[3];
    const float* r    = (const float*)d_in[4];
    const float* W1   = (const float*)d_in[5];
    const float* b1   = (const float*)d_in[6];
    const float* Wp   = (const float*)d_in[7];
    const float* bp   = (const float*)d_in[8];
    const float* Wm1  = (const float*)d_in[9];
    const float* bm1  = (const float*)d_in[10];
    const float* Wm2  = (const float*)d_in[11];
    const float* bm2  = (const float*)d_in[12];
    const float* sw   = (const float*)d_in[13];
    float* out = (float*)d_out;

    float* ws = (float*)d_ws;
    float* t_s  = ws;  ws += (size_t)BNN * CIN;
    float* t_t  = ws;  ws += (size_t)BNN * CIN;
    float* h_s  = ws;  ws += (size_t)BNN * COUT;   // reused as rt partials in loop
    float* h_t  = ws;  ws += (size_t)BNN * COUT;   // (h_s..h_t contiguous 2M floats)
    float* Sh   = ws;  ws += (size_t)NBATCH * NSEQ * NSEQ;
    float* S    = ws;  ws += (size_t)NBATCH * NSEQ * NSEQ;
    float* Sfin = ws;  ws += (size_t)NBATCH * NSEQ * NSEQ;
    float* rt   = ws;  ws += (size_t)BNN * RDIM;
    float* trs  = ws;  ws += (size_t)BNN * RDIM;
    float* trt  = ws;  ws += (size_t)BNN * RDIM;
    float* Ps   = ws;  ws += (size_t)BNN * RDIM;
    float* Pt   = ws;  ws += (size_t)BNN * RDIM;
    int* icnt  = (int*)ws;
    int* ioffs = icnt  + 2 * BNN;
    int* icur  = ioffs + 2 * (BNN + 1);
    int* issrc = icur  + 2 * BNN;   // 2*NEDGE ints
    float* rtpart = h_s;            // 16 * BNN * RDIM floats = 8 MB, dead after shat

    // ---- bucket edges by dst (both lists) ----
    hipMemsetAsync(icnt, 0, 2 * BNN * sizeof(int), stream);
    edge_hist <<<512, 256, 0, stream>>>(ei_s, ei_t, icnt);
    edge_scan <<<2, 256, 0, stream>>>(icnt, ioffs, icur);
    edge_place<<<512, 256, 0, stream>>>(ei_s, ei_t, icur, issrc);

    // ---- psi_1 for both graphs (gather form, no float atomics) ----
    gather_agg128<<<8192, 128, 0, stream>>>(x_s, x_t, ioffs, issrc, t_s, t_t);
    psi1_gemm<<<512, 256, 0, stream>>>(t_s, W1, b1, h_s);
    psi1_gemm<<<512, 256, 0, stream>>>(t_t, W1, b1, h_t);
    shat_gemm<<<dim3(16, 16, 4), 256, 0, stream>>>(h_s, h_t, Sh);

    for (int i = 0; i < 2; i++) {
        softmax_acc<<<4096, 256, 0, stream>>>(Sh, S, Sfin, sw, i, i == 0 ? 1 : 0);
        rt_part<<<dim3(16, 8, 4), 256, 0, stream>>>(S, r + (size_t)i * BNN * RDIM, rtpart);
        rt_reduce<<<128, 256, 0, stream>>>(rtpart, rt);
        gather_agg32<<<dim3(512, 2), 256, 0, stream>>>(r + (size_t)i * BNN * RDIM, rt,
                                                       ioffs, issrc, trs, trt);
        psi_r<<<512, 256, 0, stream>>>(trs, Wp + i * RDIM * RDIM, bp + i * RDIM,
                                       Wm1, bm1, Ps, 1);
        psi_r<<<512, 256, 0, stream>>>(trt, Wp + i * RDIM * RDIM, bp + i * RDIM,
                                       Wm1, bm1, Pt, 0);
        upd_add<<<dim3(16, 16, 4), 256, 0, stream>>>(Ps, Pt, Wm2, bm2, Sh);
    }
    softmax_acc<<<4096, 256, 0, stream>>>(Sh, S, Sfin, sw, 2, 0);
    softmax_out<<<4096, 256, 0, stream>>>(Sfin, out);
}

// Round 4
// 223.523 us; speedup vs baseline: 2.6146x; 1.1030x over previous
//
#include <hip/hip_runtime.h>
#include <hip/hip_bf16.h>

#define NBATCH 4
#define NSEQ   1024
#define BNN    4096
#define CIN    128
#define COUT   256
#define RDIM   32
#define NEDGE  65536

// ---------- edge bucketing (counting sort by dst) ----------
__global__ void edge_hist(const int* __restrict__ ei_s, const int* __restrict__ ei_t,
                          int* __restrict__ cnt) {
    int gid = blockIdx.x * blockDim.x + threadIdx.x;   // 2*NEDGE
    int list = gid >> 16;
    int e = gid & (NEDGE - 1);
    const int* ei = list ? ei_t : ei_s;
    atomicAdd(&cnt[list * BNN + ei[NEDGE + e]], 1);
}

__global__ void edge_scan(const int* __restrict__ cnt, int* __restrict__ offs,
                          int* __restrict__ cursor) {
    __shared__ int sums[256];
    int list = blockIdx.x;
    int tid = threadIdx.x;
    int local[16];
    int s = 0;
#pragma unroll
    for (int k = 0; k < 16; k++) { local[k] = cnt[list * BNN + tid * 16 + k]; s += local[k]; }
    sums[tid] = s;
    __syncthreads();
    for (int off = 1; off < 256; off <<= 1) {
        int v = 0;
        if (tid >= off) v = sums[tid - off];
        __syncthreads();
        if (tid >= off) sums[tid] += v;
        __syncthreads();
    }
    int run = tid ? sums[tid - 1] : 0;
#pragma unroll
    for (int k = 0; k < 16; k++) {
        offs[list * (BNN + 1) + tid * 16 + k] = run;
        cursor[list * BNN + tid * 16 + k] = run;
        run += local[k];
    }
    if (tid == 255) offs[list * (BNN + 1) + BNN] = run;
}

__global__ void edge_place(const int* __restrict__ ei_s, const int* __restrict__ ei_t,
                           int* __restrict__ cursor, int* __restrict__ ssrc) {
    int gid = blockIdx.x * blockDim.x + threadIdx.x;   // 2*NEDGE
    int list = gid >> 16;
    int e = gid & (NEDGE - 1);
    const int* ei = list ? ei_t : ei_s;
    int dst = ei[NEDGE + e], src = ei[e];
    int p = atomicAdd(&cursor[list * BNN + dst], 1);
    ssrc[list * NEDGE + p] = src;
}

// t[n] = x[n] + sum_{e: dst=n} x[src_e] (128-wide). One block (128 thr) per node.
// Neighbor list staged in LDS; 4-deep unroll keeps 4 row loads in flight.
__global__ void gather_agg128(const float* __restrict__ x_s, const float* __restrict__ x_t,
                              const int* __restrict__ offs, const int* __restrict__ ssrc,
                              float* __restrict__ t_s, float* __restrict__ t_t) {
    __shared__ int sl[128];
    int node = blockIdx.x & (BNN - 1);
    int list = blockIdx.x >> 12;
    const float* x = list ? x_t : x_s;
    float* t = list ? t_t : t_s;
    int c = threadIdx.x;
    int beg = offs[list * (BNN + 1) + node], end = offs[list * (BNN + 1) + node + 1];
    float acc = x[(size_t)node * CIN + c];
    for (int base = beg; base < end; base += 128) {
        int cnt = min(128, end - base);
        __syncthreads();
        if (c < cnt) sl[c] = ssrc[list * NEDGE + base + c];
        __syncthreads();
        int e = 0;
        for (; e + 4 <= cnt; e += 4) {
            int n0 = sl[e], n1 = sl[e + 1], n2 = sl[e + 2], n3 = sl[e + 3];
            acc += x[(size_t)n0 * CIN + c] + x[(size_t)n1 * CIN + c]
                 + x[(size_t)n2 * CIN + c] + x[(size_t)n3 * CIN + c];
        }
        for (; e < cnt; e++) acc += x[(size_t)sl[e] * CIN + c];
    }
    t[(size_t)node * CIN + c] = acc;
}

// 32-wide gather; blockIdx.y selects (rs->trs, list-s) or (rt->trt, list-t).
__global__ void gather_agg32(const float* __restrict__ rs, const float* __restrict__ rtin,
                             const int* __restrict__ offs, const int* __restrict__ ssrc,
                             float* __restrict__ trs, float* __restrict__ trt) {
    int list = blockIdx.y;
    int node = blockIdx.x * 8 + (threadIdx.x >> 5);
    int c = threadIdx.x & 31;
    const float* in = list ? rtin : rs;
    float* outp = list ? trt : trs;
    int beg = offs[list * (BNN + 1) + node], end = offs[list * (BNN + 1) + node + 1];
    float acc = in[(size_t)node * RDIM + c];
    for (int e = beg; e < end; e++)
        acc += in[(size_t)ssrc[list * NEDGE + e] * RDIM + c];
    outp[(size_t)node * RDIM + c] = acc;
}

// h = relu(t @ W1 + b1), both graphs in one launch (grid 1024).
__global__ void psi1_gemm(const float* __restrict__ t_s, const float* __restrict__ t_t,
                          const float* __restrict__ W1, const float* __restrict__ b1,
                          float* __restrict__ h_s, float* __restrict__ h_t) {
    __shared__ float rows[8][CIN];
    int half = blockIdx.x >> 9;
    const float* t = half ? t_t : t_s;
    float* h = half ? h_t : h_s;
    int r0 = (blockIdx.x & 511) * 8;
    int tid = threadIdx.x;
    {
        int rr = tid >> 5, c4 = (tid & 31) << 2;
        *(float4*)&rows[rr][c4] = *(const float4*)(t + (size_t)(r0 + rr) * CIN + c4);
    }
    __syncthreads();
    float acc[8];
    float bias = b1[tid];
#pragma unroll
    for (int r = 0; r < 8; r++) acc[r] = bias;
    for (int k = 0; k < CIN; k++) {
        float w = W1[k * COUT + tid];
#pragma unroll
        for (int r = 0; r < 8; r++) acc[r] = fmaf(rows[r][k], w, acc[r]);
    }
#pragma unroll
    for (int r = 0; r < 8; r++)
        h[(size_t)(r0 + r) * COUT + tid] = fmaxf(acc[r], 0.f);
}

// S_hat[b] = h_s[b] @ h_t[b]^T. 128x128 tile, 8x8/thread, K-panel 16, reg dbuf.
__global__ __launch_bounds__(256) void shat_gemm(const float* __restrict__ hs,
                                                 const float* __restrict__ ht,
                                                 float* __restrict__ Sh) {
    __shared__ float As[16][132];
    __shared__ float Bs[16][132];
    int b  = blockIdx.z;
    int s0 = blockIdx.y * 128, t0 = blockIdx.x * 128;
    const float* A  = hs + (size_t)b * NSEQ * COUT;
    const float* Bm = ht + (size_t)b * NSEQ * COUT;
    int tid = threadIdx.x;
    int tx = tid & 15, ty = tid >> 4;
    int lr = tid >> 1;            // 0..127
    int lk = (tid & 1) * 8;       // 0 or 8
    const float* Ap = A  + (size_t)(s0 + lr) * COUT + lk;
    const float* Bp = Bm + (size_t)(t0 + lr) * COUT + lk;
    float4 a0 = *(const float4*)(Ap);
    float4 a1 = *(const float4*)(Ap + 4);
    float4 b0 = *(const float4*)(Bp);
    float4 b1 = *(const float4*)(Bp + 4);
    float acc[8][8] = {};
    for (int kp = 0; kp < 16; kp++) {
        __syncthreads();
        As[lk + 0][lr] = a0.x; As[lk + 1][lr] = a0.y; As[lk + 2][lr] = a0.z; As[lk + 3][lr] = a0.w;
        As[lk + 4][lr] = a1.x; As[lk + 5][lr] = a1.y; As[lk + 6][lr] = a1.z; As[lk + 7][lr] = a1.w;
        Bs[lk + 0][lr] = b0.x; Bs[lk + 1][lr] = b0.y; Bs[lk + 2][lr] = b0.z; Bs[lk + 3][lr] = b0.w;
        Bs[lk + 4][lr] = b1.x; Bs[lk + 5][lr] = b1.y; Bs[lk + 6][lr] = b1.z; Bs[lk + 7][lr] = b1.w;
        __syncthreads();
        if (kp < 15) {
            a0 = *(const float4*)(Ap + (kp + 1) * 16);
            a1 = *(const float4*)(Ap + (kp + 1) * 16 + 4);
            b0 = *(const float4*)(Bp + (kp + 1) * 16);
            b1 = *(const float4*)(Bp + (kp + 1) * 16 + 4);
        }
#pragma unroll
        for (int k = 0; k < 16; k++) {
            float av[8], bv[8];
            *(float4*)&av[0] = *(const float4*)&As[k][ty * 8];
            *(float4*)&av[4] = *(const float4*)&As[k][ty * 8 + 4];
            *(float4*)&bv[0] = *(const float4*)&Bs[k][tx * 8];
            *(float4*)&bv[4] = *(const float4*)&Bs[k][tx * 8 + 4];
#pragma unroll
            for (int i = 0; i < 8; i++)
#pragma unroll
                for (int j = 0; j < 8; j++)
                    acc[i][j] = fmaf(av[i], bv[j], acc[i][j]);
        }
    }
#pragma unroll
    for (int i = 0; i < 8; i++) {
#pragma unroll
        for (int j4 = 0; j4 < 8; j4 += 4) {
            float4 v = make_float4(acc[i][j4], acc[i][j4 + 1], acc[i][j4 + 2], acc[i][j4 + 3]);
            *(float4*)(Sh + ((size_t)b * NSEQ + s0 + ty * 8 + i) * NSEQ + t0 + tx * 8 + j4) = v;
        }
    }
}

// Row softmax stats of Sh; accumulate Sfin += w*softmax(Sh). Writes m, 1/sum.
__global__ void softmax_acc2(const float* __restrict__ Sh, float* __restrict__ Sfin,
                             const float* __restrict__ sw, float* __restrict__ mstat,
                             float* __restrict__ istat, int widx, int init) {
    int row = blockIdx.x, tid = threadIdx.x;
    float4 v = *(const float4*)(Sh + (size_t)row * NSEQ + tid * 4);
    float m = fmaxf(fmaxf(v.x, v.y), fmaxf(v.z, v.w));
#pragma unroll
    for (int o = 32; o; o >>= 1) m = fmaxf(m, __shfl_xor(m, o));
    __shared__ float redm[4], reds[4];
    int wid = tid >> 6, lane = tid & 63;
    if (lane == 0) redm[wid] = m;
    __syncthreads();
    m = fmaxf(fmaxf(redm[0], redm[1]), fmaxf(redm[2], redm[3]));
    float4 e;
    e.x = __expf(v.x - m); e.y = __expf(v.y - m);
    e.z = __expf(v.z - m); e.w = __expf(v.w - m);
    float s = e.x + e.y + e.z + e.w;
#pragma unroll
    for (int o = 32; o; o >>= 1) s += __shfl_xor(s, o);
    if (lane == 0) reds[wid] = s;
    __syncthreads();
    s = reds[0] + reds[1] + reds[2] + reds[3];
    float inv = 1.0f / s;
    float w = sw[widx] * inv;
    float* fp = Sfin + (size_t)row * NSEQ + tid * 4;
    float4 f;
    if (init) {
        f = make_float4(w * e.x, w * e.y, w * e.z, w * e.w);
    } else {
        float4 old = *(const float4*)fp;
        f = make_float4(fmaf(w, e.x, old.x), fmaf(w, e.y, old.y),
                        fmaf(w, e.z, old.z), fmaf(w, e.w, old.w));
    }
    *(float4*)fp = f;
    if (tid == 0) { mstat[row] = m; istat[row] = inv; }
}

// Final: f = Sfin + w2*softmax(Sh); out = softmax(f). One block per row.
__global__ void softmax_final(const float* __restrict__ Sh, const float* __restrict__ Sfin,
                              const float* __restrict__ sw, float* __restrict__ out) {
    int row = blockIdx.x, tid = threadIdx.x;
    __shared__ float redm[4], reds[4], redm2[4], reds2[4];
    int wid = tid >> 6, lane = tid & 63;
    float4 v = *(const float4*)(Sh + (size_t)row * NSEQ + tid * 4);
    float m = fmaxf(fmaxf(v.x, v.y), fmaxf(v.z, v.w));
#pragma unroll
    for (int o = 32; o; o >>= 1) m = fmaxf(m, __shfl_xor(m, o));
    if (lane == 0) redm[wid] = m;
    __syncthreads();
    m = fmaxf(fmaxf(redm[0], redm[1]), fmaxf(redm[2], redm[3]));
    float4 e;
    e.x = __expf(v.x - m); e.y = __expf(v.y - m);
    e.z = __expf(v.z - m); e.w = __expf(v.w - m);
    float s = e.x + e.y + e.z + e.w;
#pragma unroll
    for (int o = 32; o; o >>= 1) s += __shfl_xor(s, o);
    if (lane == 0) reds[wid] = s;
    __syncthreads();
    s = reds[0] + reds[1] + reds[2] + reds[3];
    float w = sw[2] / s;
    float4 old = *(const float4*)(Sfin + (size_t)row * NSEQ + tid * 4);
    float4 f = make_float4(fmaf(w, e.x, old.x), fmaf(w, e.y, old.y),
                           fmaf(w, e.z, old.z), fmaf(w, e.w, old.w));
    // second softmax over f
    float m2 = fmaxf(fmaxf(f.x, f.y), fmaxf(f.z, f.w));
#pragma unroll
    for (int o = 32; o; o >>= 1) m2 = fmaxf(m2, __shfl_xor(m2, o));
    if (lane == 0) redm2[wid] = m2;
    __syncthreads();
    m2 = fmaxf(fmaxf(redm2[0], redm2[1]), fmaxf(redm2[2], redm2[3]));
    float4 e2;
    e2.x = __expf(f.x - m2); e2.y = __expf(f.y - m2);
    e2.z = __expf(f.z - m2); e2.w = __expf(f.w - m2);
    float s2 = e2.x + e2.y + e2.z + e2.w;
#pragma unroll
    for (int o = 32; o; o >>= 1) s2 += __shfl_xor(s2, o);
    if (lane == 0) reds2[wid] = s2;
    __syncthreads();
    s2 = reds2[0] + reds2[1] + reds2[2] + reds2[3];
    float inv2 = 1.0f / s2;
    float4 sv = make_float4(e2.x * inv2, e2.y * inv2, e2.z * inv2, e2.w * inv2);
    *(float4*)(out + (size_t)row * NSEQ + tid * 4) = sv;
}

// rt partials from Sh + row stats: part[chunk][b*NSEQ+t][j] =
//   sum_{s in chunk} exp(Sh[b,s,t]-m[s])*inv[s] * rs[b,s,j].
__global__ void rt_part(const float* __restrict__ Sh, const float* __restrict__ mstat,
                        const float* __restrict__ istat, const float* __restrict__ rs,
                        float* __restrict__ part) {
    __shared__ float rsld[64][33];
    __shared__ float ml[64], il[64];
    int b = blockIdx.z, t0 = blockIdx.y * 128, s0 = blockIdx.x * 64;
    int tid = threadIdx.x;
    if (tid < 64) ml[tid] = mstat[b * NSEQ + s0 + tid];
    else if (tid < 128) il[tid - 64] = istat[b * NSEQ + s0 + tid - 64];
#pragma unroll
    for (int q = 0; q < 2; q++) {
        int lid = (tid << 1) + q;
        int srow = lid >> 3, c4 = (lid & 7) << 2;
        float4 v = *(const float4*)(rs + ((size_t)b * NSEQ + s0 + srow) * RDIM + c4);
        rsld[srow][c4] = v.x; rsld[srow][c4 + 1] = v.y;
        rsld[srow][c4 + 2] = v.z; rsld[srow][c4 + 3] = v.w;
    }
    __syncthreads();
    int t = t0 + (tid & 127);
    int j0 = (tid >> 7) << 4;
    float acc[16] = {};
    const float* Sp = Sh + ((size_t)b * NSEQ + s0) * NSEQ + t;
#pragma unroll 8
    for (int s = 0; s < 64; s++) {
        float p = __expf(Sp[(size_t)s * NSEQ] - ml[s]) * il[s];
#pragma unroll
        for (int j = 0; j < 16; j++) acc[j] = fmaf(p, rsld[s][j0 + j], acc[j]);
    }
    float* pp = part + (((size_t)blockIdx.x * NBATCH + b) * NSEQ + t) * RDIM + j0;
#pragma unroll
    for (int j4 = 0; j4 < 16; j4 += 4)
        *(float4*)(pp + j4) = make_float4(acc[j4], acc[j4 + 1], acc[j4 + 2], acc[j4 + 3]);
}

// rt[i4] = sum over 16 chunks of part[c][i4].
__global__ void rt_reduce(const float* __restrict__ part, float* __restrict__ rt) {
    int i = blockIdx.x * blockDim.x + threadIdx.x;   // 32768 float4
    const float4* p = (const float4*)part + i;
    float4 a = make_float4(0.f, 0.f, 0.f, 0.f);
#pragma unroll
    for (int c = 0; c < 16; c++) {
        float4 v = p[(size_t)c * (BNN * RDIM / 4)];
        a.x += v.x; a.y += v.y; a.z += v.z; a.w += v.w;
    }
    ((float4*)rt)[i] = a;
}

// o = relu(t_r @ Wp + bp); P = o @ Wm1 (+ bm1 for s-side). Both sides via grid.y.
__global__ void psi_r(const float* __restrict__ trs, const float* __restrict__ trt,
                      const float* __restrict__ Wp, const float* __restrict__ bp,
                      const float* __restrict__ Wm1, const float* __restrict__ bm1,
                      float* __restrict__ Ps, float* __restrict__ Pt) {
    __shared__ float sWp[32 * 32], sWm1[32 * 32];
    __shared__ float srow[8][33], so[8][33];
    int which = blockIdx.y;
    const float* t_r = which ? trt : trs;
    float* P = which ? Pt : Ps;
    int tid = threadIdx.x;
#pragma unroll
    for (int q = 0; q < 4; q++) {
        sWp[tid + q * 256]  = Wp[tid + q * 256];
        sWm1[tid + q * 256] = Wm1[tid + q * 256];
    }
    int g = tid >> 5, j = tid & 31;
    int row = blockIdx.x * 8 + g;
    srow[g][j] = t_r[(size_t)row * RDIM + j];
    __syncthreads();
    float acc = bp[j];
#pragma unroll
    for (int k = 0; k < 32; k++) acc = fmaf(srow[g][k], sWp[k * 32 + j], acc);
    float o = fmaxf(acc, 0.f);
    so[g][j] = o;
    __syncthreads();
    float acc2 = which ? 0.f : bm1[j];
#pragma unroll
    for (int k = 0; k < 32; k++) acc2 = fmaf(so[g][k], sWm1[k * 32 + j], acc2);
    P[(size_t)row * RDIM + j] = acc2;
}

// S_hat += sum_k relu(Ps[s,k]-Pt[t,k])*Wm2[k] + bm2. 64x64 tile, 4x4/thread.
__global__ void upd_add(const float* __restrict__ Ps, const float* __restrict__ Pt,
                        const float* __restrict__ Wm2, const float* __restrict__ bm2p,
                        float* __restrict__ Sh) {
    __shared__ float sPs[64][33], sPt[64][33];
    __shared__ float swm[32];
    int b = blockIdx.z, s0 = blockIdx.y * 64, t0 = blockIdx.x * 64;
    int tid = threadIdx.x;
#pragma unroll
    for (int q = 0; q < 2; q++) {
        int lid = (tid << 1) + q, rr = lid >> 3, c4 = (lid & 7) << 2;
        float4 a = *(const float4*)(Ps + ((size_t)b * NSEQ + s0 + rr) * RDIM + c4);
        sPs[rr][c4] = a.x; sPs[rr][c4 + 1] = a.y; sPs[rr][c4 + 2] = a.z; sPs[rr][c4 + 3] = a.w;
        float4 c = *(const float4*)(Pt + ((size_t)b * NSEQ + t0 + rr) * RDIM + c4);
        sPt[rr][c4] = c.x; sPt[rr][c4 + 1] = c.y; sPt[rr][c4 + 2] = c.z; sPt[rr][c4 + 3] = c.w;
    }
    if (tid < 32) swm[tid] = Wm2[tid];
    __syncthreads();
    float bm2 = bm2p[0];
    int tx = tid & 15, ty = tid >> 4;
    float acc[4][4] = {};
#pragma unroll
    for (int k = 0; k < 32; k++) {
        float w = swm[k];
        float ps[4], pt[4];
#pragma unroll
        for (int i = 0; i < 4; i++) ps[i] = sPs[ty * 4 + i][k];
#pragma unroll
        for (int j = 0; j < 4; j++) pt[j] = sPt[tx * 4 + j][k];
#pragma unroll
        for (int i = 0; i < 4; i++)
#pragma unroll
            for (int j = 0; j < 4; j++)
                acc[i][j] = fmaf(fmaxf(ps[i] - pt[j], 0.f), w, acc[i][j]);
    }
#pragma unroll
    for (int i = 0; i < 4; i++) {
        size_t base = ((size_t)b * NSEQ + s0 + ty * 4 + i) * NSEQ + t0 + tx * 4;
        float4 old = *(const float4*)(Sh + base);
        old.x += acc[i][0] + bm2; old.y += acc[i][1] + bm2;
        old.z += acc[i][2] + bm2; old.w += acc[i][3] + bm2;
        *(float4*)(Sh + base) = old;
    }
}

extern "C" void kernel_launch(void* const* d_in, const int* in_sizes, int n_in,
                              void* d_out, int out_size, void* d_ws, size_t ws_size,
                              hipStream_t stream) {
    const float* x_s  = (const float*)d_in[0];
    const int*   ei_s = (const int*)  d_in[1];
    const float* x_t  = (const float*)d_in[2];
    const int*   ei_t = (const int*)  d_in[3];
    const float* r    = (const float*)d_in[4];
    const float* W1   = (const float*)d_in[5];
    const float* b1   = (const float*)d_in[6];
    const float* Wp   = (const float*)d_in[7];
    const float* bp   = (const float*)d_in[8];
    const float* Wm1  = (const float*)d_in[9];
    const float* bm1  = (const float*)d_in[10];
    const float* Wm2  = (const float*)d_in[11];
    const float* bm2  = (const float*)d_in[12];
    const float* sw   = (const float*)d_in[13];
    float* out = (float*)d_out;

    float* ws = (float*)d_ws;
    float* t_s  = ws;  ws += (size_t)BNN * CIN;
    float* t_t  = ws;  ws += (size_t)BNN * CIN;
    float* h_s  = ws;  ws += (size_t)BNN * COUT;   // reused as rt partials in loop
    float* h_t  = ws;  ws += (size_t)BNN * COUT;   // (h_s..h_t contiguous 2M floats)
    float* Sh   = ws;  ws += (size_t)NBATCH * NSEQ * NSEQ;
    float* Sfin = ws;  ws += (size_t)NBATCH * NSEQ * NSEQ;
    float* mstat = ws; ws += BNN;
    float* istat = ws; ws += BNN;
    float* rt   = ws;  ws += (size_t)BNN * RDIM;
    float* trs  = ws;  ws += (size_t)BNN * RDIM;
    float* trt  = ws;  ws += (size_t)BNN * RDIM;
    float* Ps   = ws;  ws += (size_t)BNN * RDIM;
    float* Pt   = ws;  ws += (size_t)BNN * RDIM;
    int* icnt  = (int*)ws;
    int* ioffs = icnt  + 2 * BNN;
    int* icur  = ioffs + 2 * (BNN + 1);
    int* issrc = icur  + 2 * BNN;   // 2*NEDGE ints
    float* rtpart = h_s;            // 16*BNN*RDIM floats = 8 MB, dead after shat

    // ---- bucket edges by dst (both lists) ----
    hipMemsetAsync(icnt, 0, 2 * BNN * sizeof(int), stream);
    edge_hist <<<512, 256, 0, stream>>>(ei_s, ei_t, icnt);
    edge_scan <<<2, 256, 0, stream>>>(icnt, ioffs, icur);
    edge_place<<<512, 256, 0, stream>>>(ei_s, ei_t, icur, issrc);

    // ---- psi_1 for both graphs ----
    gather_agg128<<<8192, 128, 0, stream>>>(x_s, x_t, ioffs, issrc, t_s, t_t);
    psi1_gemm<<<1024, 256, 0, stream>>>(t_s, t_t, W1, b1, h_s, h_t);
    shat_gemm<<<dim3(8, 8, 4), 256, 0, stream>>>(h_s, h_t, Sh);

    for (int i = 0; i < 2; i++) {
        softmax_acc2<<<4096, 256, 0, stream>>>(Sh, Sfin, sw, mstat, istat, i, i == 0 ? 1 : 0);
        rt_part<<<dim3(16, 8, 4), 256, 0, stream>>>(Sh, mstat, istat,
                                                    r + (size_t)i * BNN * RDIM, rtpart);
        rt_reduce<<<128, 256, 0, stream>>>(rtpart, rt);
        gather_agg32<<<dim3(512, 2), 256, 0, stream>>>(r + (size_t)i * BNN * RDIM, rt,
                                                       ioffs, issrc, trs, trt);
        psi_r<<<dim3(512, 2), 256, 0, stream>>>(trs, trt, Wp + i * RDIM * RDIM,
                                                bp + i * RDIM, Wm1, bm1, Ps, Pt);
        upd_add<<<dim3(16, 16, 4), 256, 0, stream>>>(Ps, Pt, Wm2, bm2, Sh);
    }
    softmax_final<<<4096, 256, 0, stream>>>(Sh, Sfin, sw, out);
}

// Round 5
// 214.475 us; speedup vs baseline: 2.7249x; 1.0422x over previous
//
#include <hip/hip_runtime.h>
#include <hip/hip_bf16.h>

#define NBATCH 4
#define NSEQ   1024
#define BNN    4096
#define CIN    128
#define COUT   256
#define RDIM   32
#define NEDGE  65536

// ---------- edge bucketing (counting sort by dst) ----------
__global__ void edge_hist(const int* __restrict__ ei_s, const int* __restrict__ ei_t,
                          int* __restrict__ cnt) {
    int gid = blockIdx.x * blockDim.x + threadIdx.x;   // 2*NEDGE
    int list = gid >> 16;
    int e = gid & (NEDGE - 1);
    const int* ei = list ? ei_t : ei_s;
    atomicAdd(&cnt[list * BNN + ei[NEDGE + e]], 1);
}

__global__ void edge_scan(const int* __restrict__ cnt, int* __restrict__ offs,
                          int* __restrict__ cursor) {
    __shared__ int sums[256];
    int list = blockIdx.x;
    int tid = threadIdx.x;
    int local[16];
    int s = 0;
#pragma unroll
    for (int k = 0; k < 16; k++) { local[k] = cnt[list * BNN + tid * 16 + k]; s += local[k]; }
    sums[tid] = s;
    __syncthreads();
    for (int off = 1; off < 256; off <<= 1) {
        int v = 0;
        if (tid >= off) v = sums[tid - off];
        __syncthreads();
        if (tid >= off) sums[tid] += v;
        __syncthreads();
    }
    int run = tid ? sums[tid - 1] : 0;
#pragma unroll
    for (int k = 0; k < 16; k++) {
        offs[list * (BNN + 1) + tid * 16 + k] = run;
        cursor[list * BNN + tid * 16 + k] = run;
        run += local[k];
    }
    if (tid == 255) offs[list * (BNN + 1) + BNN] = run;
}

__global__ void edge_place(const int* __restrict__ ei_s, const int* __restrict__ ei_t,
                           int* __restrict__ cursor, int* __restrict__ ssrc) {
    int gid = blockIdx.x * blockDim.x + threadIdx.x;   // 2*NEDGE
    int list = gid >> 16;
    int e = gid & (NEDGE - 1);
    const int* ei = list ? ei_t : ei_s;
    int dst = ei[NEDGE + e], src = ei[e];
    int p = atomicAdd(&cursor[list * BNN + dst], 1);
    ssrc[list * NEDGE + p] = src;
}

// t[n] = x[n] + sum_{e: dst=n} x[src_e] (128-wide). One block (128 thr) per node.
__global__ void gather_agg128(const float* __restrict__ x_s, const float* __restrict__ x_t,
                              const int* __restrict__ offs, const int* __restrict__ ssrc,
                              float* __restrict__ t_s, float* __restrict__ t_t) {
    __shared__ int sl[128];
    int node = blockIdx.x & (BNN - 1);
    int list = blockIdx.x >> 12;
    const float* x = list ? x_t : x_s;
    float* t = list ? t_t : t_s;
    int c = threadIdx.x;
    int beg = offs[list * (BNN + 1) + node], end = offs[list * (BNN + 1) + node + 1];
    float acc = x[(size_t)node * CIN + c];
    for (int base = beg; base < end; base += 128) {
        int cnt = min(128, end - base);
        __syncthreads();
        if (c < cnt) sl[c] = ssrc[list * NEDGE + base + c];
        __syncthreads();
        int e = 0;
        for (; e + 4 <= cnt; e += 4) {
            int n0 = sl[e], n1 = sl[e + 1], n2 = sl[e + 2], n3 = sl[e + 3];
            acc += x[(size_t)n0 * CIN + c] + x[(size_t)n1 * CIN + c]
                 + x[(size_t)n2 * CIN + c] + x[(size_t)n3 * CIN + c];
        }
        for (; e < cnt; e++) acc += x[(size_t)sl[e] * CIN + c];
    }
    t[(size_t)node * CIN + c] = acc;
}

// 32-wide gather; blockIdx.y selects (rs->trs, list-s) or (rt->trt, list-t).
__global__ void gather_agg32(const float* __restrict__ rs, const float* __restrict__ rtin,
                             const int* __restrict__ offs, const int* __restrict__ ssrc,
                             float* __restrict__ trs, float* __restrict__ trt) {
    int list = blockIdx.y;
    int node = blockIdx.x * 8 + (threadIdx.x >> 5);
    int c = threadIdx.x & 31;
    const float* in = list ? rtin : rs;
    float* outp = list ? trt : trs;
    int beg = offs[list * (BNN + 1) + node], end = offs[list * (BNN + 1) + node + 1];
    float acc = in[(size_t)node * RDIM + c];
    for (int e = beg; e < end; e++)
        acc += in[(size_t)ssrc[list * NEDGE + e] * RDIM + c];
    outp[(size_t)node * RDIM + c] = acc;
}

// h = relu(t @ W1 + b1), both graphs in one launch (grid 1024).
__global__ void psi1_gemm(const float* __restrict__ t_s, const float* __restrict__ t_t,
                          const float* __restrict__ W1, const float* __restrict__ b1,
                          float* __restrict__ h_s, float* __restrict__ h_t) {
    __shared__ float rows[8][CIN];
    int half = blockIdx.x >> 9;
    const float* t = half ? t_t : t_s;
    float* h = half ? h_t : h_s;
    int r0 = (blockIdx.x & 511) * 8;
    int tid = threadIdx.x;
    {
        int rr = tid >> 5, c4 = (tid & 31) << 2;
        *(float4*)&rows[rr][c4] = *(const float4*)(t + (size_t)(r0 + rr) * CIN + c4);
    }
    __syncthreads();
    float acc[8];
    float bias = b1[tid];
#pragma unroll
    for (int r = 0; r < 8; r++) acc[r] = bias;
    for (int k = 0; k < CIN; k++) {
        float w = W1[k * COUT + tid];
#pragma unroll
        for (int r = 0; r < 8; r++) acc[r] = fmaf(rows[r][k], w, acc[r]);
    }
#pragma unroll
    for (int r = 0; r < 8; r++)
        h[(size_t)(r0 + r) * COUT + tid] = fmaxf(acc[r], 0.f);
}

// S_hat[b] = h_s[b] @ h_t[b]^T. 128(s)x64(t) tile, acc[8][4], 512 blocks, K-panel 16.
// Conflict-free LDS: A-frag reads broadcast per 16-lane group; B float4 at stride 16B (2-way).
__global__ __launch_bounds__(256) void shat_gemm(const float* __restrict__ hs,
                                                 const float* __restrict__ ht,
                                                 float* __restrict__ Sh) {
    __shared__ float As[16][132];
    __shared__ float Bs[16][68];
    int b  = blockIdx.z;
    int s0 = blockIdx.y * 128, t0 = blockIdx.x * 64;
    const float* A  = hs + (size_t)b * NSEQ * COUT;
    const float* Bm = ht + (size_t)b * NSEQ * COUT;
    int tid = threadIdx.x;
    int tx = tid & 15, ty = tid >> 4;   // tx -> 4 t-cols, ty -> 8 s-rows
    int lrA = tid >> 1,  lkA = (tid & 1) * 8;   // A stage: 128 rows x 16 k
    int lrB = tid >> 2,  lkB = (tid & 3) * 4;   // B stage:  64 rows x 16 k
    const float* Ap = A  + (size_t)(s0 + lrA) * COUT + lkA;
    const float* Bp = Bm + (size_t)(t0 + lrB) * COUT + lkB;
    float4 a0 = *(const float4*)(Ap);
    float4 a1 = *(const float4*)(Ap + 4);
    float4 b0 = *(const float4*)(Bp);
    float acc[8][4] = {};
    for (int kp = 0; kp < 16; kp++) {
        __syncthreads();
        As[lkA + 0][lrA] = a0.x; As[lkA + 1][lrA] = a0.y;
        As[lkA + 2][lrA] = a0.z; As[lkA + 3][lrA] = a0.w;
        As[lkA + 4][lrA] = a1.x; As[lkA + 5][lrA] = a1.y;
        As[lkA + 6][lrA] = a1.z; As[lkA + 7][lrA] = a1.w;
        Bs[lkB + 0][lrB] = b0.x; Bs[lkB + 1][lrB] = b0.y;
        Bs[lkB + 2][lrB] = b0.z; Bs[lkB + 3][lrB] = b0.w;
        __syncthreads();
        if (kp < 15) {
            a0 = *(const float4*)(Ap + (kp + 1) * 16);
            a1 = *(const float4*)(Ap + (kp + 1) * 16 + 4);
            b0 = *(const float4*)(Bp + (kp + 1) * 16);
        }
#pragma unroll
        for (int k = 0; k < 16; k++) {
            float av[8], bv[4];
            *(float4*)&av[0] = *(const float4*)&As[k][ty * 8];
            *(float4*)&av[4] = *(const float4*)&As[k][ty * 8 + 4];
            *(float4*)&bv[0] = *(const float4*)&Bs[k][tx * 4];
#pragma unroll
            for (int i = 0; i < 8; i++)
#pragma unroll
                for (int j = 0; j < 4; j++)
                    acc[i][j] = fmaf(av[i], bv[j], acc[i][j]);
        }
    }
#pragma unroll
    for (int i = 0; i < 8; i++) {
        float4 v = make_float4(acc[i][0], acc[i][1], acc[i][2], acc[i][3]);
        *(float4*)(Sh + ((size_t)b * NSEQ + s0 + ty * 8 + i) * NSEQ + t0 + tx * 4) = v;
    }
}

// Row softmax stats of Sh: mstat[row]=max, istat[row]=1/sum. One block per row.
__global__ void softmax_stats(const float* __restrict__ Sh, float* __restrict__ mstat,
                              float* __restrict__ istat) {
    int row = blockIdx.x, tid = threadIdx.x;
    float4 v = *(const float4*)(Sh + (size_t)row * NSEQ + tid * 4);
    float m = fmaxf(fmaxf(v.x, v.y), fmaxf(v.z, v.w));
#pragma unroll
    for (int o = 32; o; o >>= 1) m = fmaxf(m, __shfl_xor(m, o));
    __shared__ float redm[4], reds[4];
    int wid = tid >> 6, lane = tid & 63;
    if (lane == 0) redm[wid] = m;
    __syncthreads();
    m = fmaxf(fmaxf(redm[0], redm[1]), fmaxf(redm[2], redm[3]));
    float s = __expf(v.x - m) + __expf(v.y - m) + __expf(v.z - m) + __expf(v.w - m);
#pragma unroll
    for (int o = 32; o; o >>= 1) s += __shfl_xor(s, o);
    if (lane == 0) reds[wid] = s;
    __syncthreads();
    if (tid == 0) {
        float tot = reds[0] + reds[1] + reds[2] + reds[3];
        mstat[row] = m;
        istat[row] = 1.0f / tot;
    }
}

// Final: f = sum_i sw[i]*softmax(Sh_i); out = softmax(f). One block per row.
__global__ void softmax_final3(const float* __restrict__ Sh0, const float* __restrict__ Sh1,
                               const float* __restrict__ Sh2, const float* __restrict__ m0a,
                               const float* __restrict__ i0a, const float* __restrict__ m1a,
                               const float* __restrict__ i1a, const float* __restrict__ sw,
                               float* __restrict__ out) {
    int row = blockIdx.x, tid = threadIdx.x;
    __shared__ float red[4];
    int wid = tid >> 6, lane = tid & 63;
    float4 v0 = *(const float4*)(Sh0 + (size_t)row * NSEQ + tid * 4);
    float4 v1 = *(const float4*)(Sh1 + (size_t)row * NSEQ + tid * 4);
    float4 v2 = *(const float4*)(Sh2 + (size_t)row * NSEQ + tid * 4);
    // stats of Sh2 in-register
    float m2 = fmaxf(fmaxf(v2.x, v2.y), fmaxf(v2.z, v2.w));
#pragma unroll
    for (int o = 32; o; o >>= 1) m2 = fmaxf(m2, __shfl_xor(m2, o));
    if (lane == 0) red[wid] = m2;
    __syncthreads();
    m2 = fmaxf(fmaxf(red[0], red[1]), fmaxf(red[2], red[3]));
    __syncthreads();
    float4 e2;
    e2.x = __expf(v2.x - m2); e2.y = __expf(v2.y - m2);
    e2.z = __expf(v2.z - m2); e2.w = __expf(v2.w - m2);
    float s2 = e2.x + e2.y + e2.z + e2.w;
#pragma unroll
    for (int o = 32; o; o >>= 1) s2 += __shfl_xor(s2, o);
    if (lane == 0) red[wid] = s2;
    __syncthreads();
    s2 = red[0] + red[1] + red[2] + red[3];
    __syncthreads();
    float w0 = sw[0] * i0a[row], w1 = sw[1] * i1a[row], w2 = sw[2] / s2;
    float m0 = m0a[row], m1 = m1a[row];
    float4 f;
    f.x = fmaf(w0, __expf(v0.x - m0), fmaf(w1, __expf(v1.x - m1), w2 * e2.x));
    f.y = fmaf(w0, __expf(v0.y - m0), fmaf(w1, __expf(v1.y - m1), w2 * e2.y));
    f.z = fmaf(w0, __expf(v0.z - m0), fmaf(w1, __expf(v1.z - m1), w2 * e2.z));
    f.w = fmaf(w0, __expf(v0.w - m0), fmaf(w1, __expf(v1.w - m1), w2 * e2.w));
    // softmax over f
    float mf = fmaxf(fmaxf(f.x, f.y), fmaxf(f.z, f.w));
#pragma unroll
    for (int o = 32; o; o >>= 1) mf = fmaxf(mf, __shfl_xor(mf, o));
    if (lane == 0) red[wid] = mf;
    __syncthreads();
    mf = fmaxf(fmaxf(red[0], red[1]), fmaxf(red[2], red[3]));
    __syncthreads();
    float4 ef;
    ef.x = __expf(f.x - mf); ef.y = __expf(f.y - mf);
    ef.z = __expf(f.z - mf); ef.w = __expf(f.w - mf);
    float sf = ef.x + ef.y + ef.z + ef.w;
#pragma unroll
    for (int o = 32; o; o >>= 1) sf += __shfl_xor(sf, o);
    if (lane == 0) red[wid] = sf;
    __syncthreads();
    sf = red[0] + red[1] + red[2] + red[3];
    float inv = 1.0f / sf;
    float4 sv = make_float4(ef.x * inv, ef.y * inv, ef.z * inv, ef.w * inv);
    *(float4*)(out + (size_t)row * NSEQ + tid * 4) = sv;
}

// rt partials from Sh + row stats.
__global__ void rt_part(const float* __restrict__ Sh, const float* __restrict__ mstat,
                        const float* __restrict__ istat, const float* __restrict__ rs,
                        float* __restrict__ part) {
    __shared__ float rsld[64][33];
    __shared__ float ml[64], il[64];
    int b = blockIdx.z, t0 = blockIdx.y * 128, s0 = blockIdx.x * 64;
    int tid = threadIdx.x;
    if (tid < 64) ml[tid] = mstat[b * NSEQ + s0 + tid];
    else if (tid < 128) il[tid - 64] = istat[b * NSEQ + s0 + tid - 64];
#pragma unroll
    for (int q = 0; q < 2; q++) {
        int lid = (tid << 1) + q;
        int srow = lid >> 3, c4 = (lid & 7) << 2;
        float4 v = *(const float4*)(rs + ((size_t)b * NSEQ + s0 + srow) * RDIM + c4);
        rsld[srow][c4] = v.x; rsld[srow][c4 + 1] = v.y;
        rsld[srow][c4 + 2] = v.z; rsld[srow][c4 + 3] = v.w;
    }
    __syncthreads();
    int t = t0 + (tid & 127);
    int j0 = (tid >> 7) << 4;
    float acc[16] = {};
    const float* Sp = Sh + ((size_t)b * NSEQ + s0) * NSEQ + t;
#pragma unroll 8
    for (int s = 0; s < 64; s++) {
        float p = __expf(Sp[(size_t)s * NSEQ] - ml[s]) * il[s];
#pragma unroll
        for (int j = 0; j < 16; j++) acc[j] = fmaf(p, rsld[s][j0 + j], acc[j]);
    }
    float* pp = part + (((size_t)blockIdx.x * NBATCH + b) * NSEQ + t) * RDIM + j0;
#pragma unroll
    for (int j4 = 0; j4 < 16; j4 += 4)
        *(float4*)(pp + j4) = make_float4(acc[j4], acc[j4 + 1], acc[j4 + 2], acc[j4 + 3]);
}

// rt[i4] = sum over 16 chunks of part[c][i4].
__global__ void rt_reduce(const float* __restrict__ part, float* __restrict__ rt) {
    int i = blockIdx.x * blockDim.x + threadIdx.x;   // 32768 float4
    const float4* p = (const float4*)part + i;
    float4 a = make_float4(0.f, 0.f, 0.f, 0.f);
#pragma unroll
    for (int c = 0; c < 16; c++) {
        float4 v = p[(size_t)c * (BNN * RDIM / 4)];
        a.x += v.x; a.y += v.y; a.z += v.z; a.w += v.w;
    }
    ((float4*)rt)[i] = a;
}

// o = relu(t_r @ Wp + bp); P = o @ Wm1 (+ bm1 for s-side). Both sides via grid.y.
__global__ void psi_r(const float* __restrict__ trs, const float* __restrict__ trt,
                      const float* __restrict__ Wp, const float* __restrict__ bp,
                      const float* __restrict__ Wm1, const float* __restrict__ bm1,
                      float* __restrict__ Ps, float* __restrict__ Pt) {
    __shared__ float sWp[32 * 32], sWm1[32 * 32];
    __shared__ float srow[8][33], so[8][33];
    int which = blockIdx.y;
    const float* t_r = which ? trt : trs;
    float* P = which ? Pt : Ps;
    int tid = threadIdx.x;
#pragma unroll
    for (int q = 0; q < 4; q++) {
        sWp[tid + q * 256]  = Wp[tid + q * 256];
        sWm1[tid + q * 256] = Wm1[tid + q * 256];
    }
    int g = tid >> 5, j = tid & 31;
    int row = blockIdx.x * 8 + g;
    srow[g][j] = t_r[(size_t)row * RDIM + j];
    __syncthreads();
    float acc = bp[j];
#pragma unroll
    for (int k = 0; k < 32; k++) acc = fmaf(srow[g][k], sWp[k * 32 + j], acc);
    float o = fmaxf(acc, 0.f);
    so[g][j] = o;
    __syncthreads();
    float acc2 = which ? 0.f : bm1[j];
#pragma unroll
    for (int k = 0; k < 32; k++) acc2 = fmaf(so[g][k], sWm1[k * 32 + j], acc2);
    P[(size_t)row * RDIM + j] = acc2;
}

// Shout = Shin + upd, upd = sum_k relu(Ps[s,k]-Pt[t,k])*Wm2[k] + bm2. 64x64 tile.
__global__ void upd_add(const float* __restrict__ Ps, const float* __restrict__ Pt,
                        const float* __restrict__ Wm2, const float* __restrict__ bm2p,
                        const float* __restrict__ Shin, float* __restrict__ Shout) {
    __shared__ float sPs[64][33], sPt[64][33];
    __shared__ float swm[32];
    int b = blockIdx.z, s0 = blockIdx.y * 64, t0 = blockIdx.x * 64;
    int tid = threadIdx.x;
#pragma unroll
    for (int q = 0; q < 2; q++) {
        int lid = (tid << 1) + q, rr = lid >> 3, c4 = (lid & 7) << 2;
        float4 a = *(const float4*)(Ps + ((size_t)b * NSEQ + s0 + rr) * RDIM + c4);
        sPs[rr][c4] = a.x; sPs[rr][c4 + 1] = a.y; sPs[rr][c4 + 2] = a.z; sPs[rr][c4 + 3] = a.w;
        float4 c = *(const float4*)(Pt + ((size_t)b * NSEQ + t0 + rr) * RDIM + c4);
        sPt[rr][c4] = c.x; sPt[rr][c4 + 1] = c.y; sPt[rr][c4 + 2] = c.z; sPt[rr][c4 + 3] = c.w;
    }
    if (tid < 32) swm[tid] = Wm2[tid];
    __syncthreads();
    float bm2 = bm2p[0];
    int tx = tid & 15, ty = tid >> 4;
    float acc[4][4] = {};
#pragma unroll
    for (int k = 0; k < 32; k++) {
        float w = swm[k];
        float ps[4], pt[4];
#pragma unroll
        for (int i = 0; i < 4; i++) ps[i] = sPs[ty * 4 + i][k];
#pragma unroll
        for (int j = 0; j < 4; j++) pt[j] = sPt[tx * 4 + j][k];
#pragma unroll
        for (int i = 0; i < 4; i++)
#pragma unroll
            for (int j = 0; j < 4; j++)
                acc[i][j] = fmaf(fmaxf(ps[i] - pt[j], 0.f), w, acc[i][j]);
    }
#pragma unroll
    for (int i = 0; i < 4; i++) {
        size_t base = ((size_t)b * NSEQ + s0 + ty * 4 + i) * NSEQ + t0 + tx * 4;
        float4 old = *(const float4*)(Shin + base);
        old.x += acc[i][0] + bm2; old.y += acc[i][1] + bm2;
        old.z += acc[i][2] + bm2; old.w += acc[i][3] + bm2;
        *(float4*)(Shout + base) = old;
    }
}

extern "C" void kernel_launch(void* const* d_in, const int* in_sizes, int n_in,
                              void* d_out, int out_size, void* d_ws, size_t ws_size,
                              hipStream_t stream) {
    const float* x_s  = (const float*)d_in[0];
    const int*   ei_s = (const int*)  d_in[1];
    const float* x_t  = (const float*)d_in[2];
    const int*   ei_t = (const int*)  d_in[3];
    const float* r    = (const float*)d_in[4];
    const float* W1   = (const float*)d_in[5];
    const float* b1   = (const float*)d_in[6];
    const float* Wp   = (const float*)d_in[7];
    const float* bp   = (const float*)d_in[8];
    const float* Wm1  = (const float*)d_in[9];
    const float* bm1  = (const float*)d_in[10];
    const float* Wm2  = (const float*)d_in[11];
    const float* bm2  = (const float*)d_in[12];
    const float* sw   = (const float*)d_in[13];
    float* out = (float*)d_out;

    float* ws = (float*)d_ws;
    float* t_s  = ws;  ws += (size_t)BNN * CIN;
    float* t_t  = ws;  ws += (size_t)BNN * CIN;
    float* h_s  = ws;  ws += (size_t)BNN * COUT;   // reused as rt partials in loop
    float* h_t  = ws;  ws += (size_t)BNN * COUT;
    float* Sh0  = ws;  ws += (size_t)NBATCH * NSEQ * NSEQ;
    float* Sh1  = ws;  ws += (size_t)NBATCH * NSEQ * NSEQ;
    float* Sh2  = ws;  ws += (size_t)NBATCH * NSEQ * NSEQ;
    float* mstat = ws; ws += 2 * BNN;
    float* istat = ws; ws += 2 * BNN;
    float* rt   = ws;  ws += (size_t)BNN * RDIM;
    float* trs  = ws;  ws += (size_t)BNN * RDIM;
    float* trt  = ws;  ws += (size_t)BNN * RDIM;
    float* Ps   = ws;  ws += (size_t)BNN * RDIM;
    float* Pt   = ws;  ws += (size_t)BNN * RDIM;
    int* icnt  = (int*)ws;
    int* ioffs = icnt  + 2 * BNN;
    int* icur  = ioffs + 2 * (BNN + 1);
    int* issrc = icur  + 2 * BNN;   // 2*NEDGE ints
    float* rtpart = h_s;            // 16*BNN*RDIM floats = 8 MB, dead after shat

    float* ShA[3] = {Sh0, Sh1, Sh2};

    // ---- bucket edges by dst (both lists) ----
    hipMemsetAsync(icnt, 0, 2 * BNN * sizeof(int), stream);
    edge_hist <<<512, 256, 0, stream>>>(ei_s, ei_t, icnt);
    edge_scan <<<2, 256, 0, stream>>>(icnt, ioffs, icur);
    edge_place<<<512, 256, 0, stream>>>(ei_s, ei_t, icur, issrc);

    // ---- psi_1 for both graphs ----
    gather_agg128<<<8192, 128, 0, stream>>>(x_s, x_t, ioffs, issrc, t_s, t_t);
    psi1_gemm<<<1024, 256, 0, stream>>>(t_s, t_t, W1, b1, h_s, h_t);
    shat_gemm<<<dim3(16, 8, 4), 256, 0, stream>>>(h_s, h_t, Sh0);

    for (int i = 0; i < 2; i++) {
        softmax_stats<<<4096, 256, 0, stream>>>(ShA[i], mstat + i * BNN, istat + i * BNN);
        rt_part<<<dim3(16, 8, 4), 256, 0, stream>>>(ShA[i], mstat + i * BNN, istat + i * BNN,
                                                    r + (size_t)i * BNN * RDIM, rtpart);
        rt_reduce<<<128, 256, 0, stream>>>(rtpart, rt);
        gather_agg32<<<dim3(512, 2), 256, 0, stream>>>(r + (size_t)i * BNN * RDIM, rt,
                                                       ioffs, issrc, trs, trt);
        psi_r<<<dim3(512, 2), 256, 0, stream>>>(trs, trt, Wp + i * RDIM * RDIM,
                                                bp + i * RDIM, Wm1, bm1, Ps, Pt);
        upd_add<<<dim3(16, 16, 4), 256, 0, stream>>>(Ps, Pt, Wm2, bm2, ShA[i], ShA[i + 1]);
    }
    softmax_final3<<<4096, 256, 0, stream>>>(Sh0, Sh1, Sh2, mstat, istat,
                                             mstat + BNN, istat + BNN, sw, out);
}